// Round 2
// baseline (6322.783 us; speedup 1.0000x reference)
//
#include <hip/hip_runtime.h>

#define NN 50000
#define NE 800000
#define CIN 64
#define COUT 64
#define HD 32
#define NL 4

__device__ __forceinline__ float silu_f(float v) {
    return v * __builtin_amdgcn_rcpf(1.0f + __expf(-v));
}

// ---------------- embed: h = [t, data] @ W + b ; x = [pos, 0] ----------------
__global__ __launch_bounds__(256) void embed_kernel(
    const float* __restrict__ data, const float* __restrict__ pos,
    const float* __restrict__ tptr,
    const float* __restrict__ W, const float* __restrict__ b,
    float* __restrict__ h, float* __restrict__ x)
{
    int n = blockIdx.x * 256 + threadIdx.x;
    if (n >= NN) return;
    float t = tptr[0];
    float d[CIN];
    const float4* dp = (const float4*)(data + (size_t)n * CIN);
#pragma unroll
    for (int i = 0; i < CIN / 4; i++) {
        float4 v = dp[i];
        d[4*i+0] = v.x; d[4*i+1] = v.y; d[4*i+2] = v.z; d[4*i+3] = v.w;
    }
    float acc[HD];
#pragma unroll
    for (int j = 0; j < HD; j++) acc[j] = fmaf(t, W[j], b[j]);   // row 0 of W is the t channel
#pragma unroll
    for (int i = 0; i < CIN; i++) {
        float a = d[i];
#pragma unroll
        for (int j = 0; j < HD; j++) acc[j] = fmaf(a, W[(i + 1) * HD + j], acc[j]);
    }
    float4* hp = (float4*)(h + (size_t)n * HD);
#pragma unroll
    for (int j = 0; j < HD / 4; j++)
        hp[j] = make_float4(acc[4*j], acc[4*j+1], acc[4*j+2], acc[4*j+3]);
    x[n * 3 + 0] = pos[n * 2 + 0];
    x[n * 3 + 1] = pos[n * 2 + 1];
    x[n * 3 + 2] = 0.0f;
}

// ---------------- degree count ----------------
__global__ __launch_bounds__(256) void cnt_kernel(const int* __restrict__ row,
                                                  float* __restrict__ cnt)
{
    int e = blockIdx.x * 256 + threadIdx.x;
    if (e < NE) atomicAdd(&cnt[row[e]], 1.0f);
}

// ---------------- fused edge kernel: edge MLP + coord MLP + scatter ----------------
__global__ __launch_bounds__(256) void edge_kernel(
    const float* __restrict__ h, const float* __restrict__ x,
    const float* __restrict__ edge_attr,
    const int* __restrict__ row, const int* __restrict__ col,
    const float* __restrict__ eW1, const float* __restrict__ eb1,
    const float* __restrict__ eW2, const float* __restrict__ eb2,
    const float* __restrict__ cW1, const float* __restrict__ cb1,
    const float* __restrict__ cW2,
    float* __restrict__ aggM, float* __restrict__ aggX)
{
    int e = blockIdx.x * 256 + threadIdx.x;
    if (e >= NE) return;
    int r = row[e], c = col[e];

    float xr0 = x[r*3+0], xr1 = x[r*3+1], xr2 = x[r*3+2];
    float xc0 = x[c*3+0], xc1 = x[c*3+1], xc2 = x[c*3+2];
    float d0 = xr0 - xc0, d1 = xr1 - xc1, d2 = xr2 - xc2;
    float radial = d0*d0 + d1*d1 + d2*d2;

    float ein[2*HD+2];
    const float4* hr = (const float4*)(h + (size_t)r * HD);
    const float4* hc = (const float4*)(h + (size_t)c * HD);
#pragma unroll
    for (int i = 0; i < HD/4; i++) {
        float4 v = hr[i];
        ein[4*i+0] = v.x; ein[4*i+1] = v.y; ein[4*i+2] = v.z; ein[4*i+3] = v.w;
    }
#pragma unroll
    for (int i = 0; i < HD/4; i++) {
        float4 v = hc[i];
        ein[HD+4*i+0] = v.x; ein[HD+4*i+1] = v.y; ein[HD+4*i+2] = v.z; ein[HD+4*i+3] = v.w;
    }
    ein[2*HD+0] = radial;
    ein[2*HD+1] = edge_attr[e];

    // GEMM1: 66 -> 32, silu
    float t1[HD];
#pragma unroll
    for (int j = 0; j < HD; j++) t1[j] = eb1[j];
#pragma unroll
    for (int i = 0; i < 2*HD+2; i++) {
        float a = ein[i];
#pragma unroll
        for (int j = 0; j < HD; j++) t1[j] = fmaf(a, eW1[i * HD + j], t1[j]);
    }
#pragma unroll
    for (int j = 0; j < HD; j++) t1[j] = silu_f(t1[j]);

    // GEMM2: 32 -> 32, silu -> m
    float m[HD];
#pragma unroll
    for (int j = 0; j < HD; j++) m[j] = eb2[j];
#pragma unroll
    for (int i = 0; i < HD; i++) {
        float a = t1[i];
#pragma unroll
        for (int j = 0; j < HD; j++) m[j] = fmaf(a, eW2[i * HD + j], m[j]);
    }
#pragma unroll
    for (int j = 0; j < HD; j++) m[j] = silu_f(m[j]);

    // coord MLP: m -> 32 (silu) -> 1
    float c1[HD];
#pragma unroll
    for (int j = 0; j < HD; j++) c1[j] = cb1[j];
#pragma unroll
    for (int i = 0; i < HD; i++) {
        float a = m[i];
#pragma unroll
        for (int j = 0; j < HD; j++) c1[j] = fmaf(a, cW1[i * HD + j], c1[j]);
    }
    float phi = 0.0f;
#pragma unroll
    for (int j = 0; j < HD; j++) phi = fmaf(silu_f(c1[j]), cW2[j], phi);

    // scatter: coord aggregation and message aggregation onto row
    atomicAdd(&aggX[r*3+0], d0 * phi);
    atomicAdd(&aggX[r*3+1], d1 * phi);
    atomicAdd(&aggX[r*3+2], d2 * phi);
#pragma unroll
    for (int j = 0; j < HD; j++) atomicAdd(&aggM[(size_t)r * HD + j], m[j]);
}

// ---------------- node update: x += aggX/cnt ; h += MLP([h, aggM]) ----------------
__global__ __launch_bounds__(256) void node_kernel(
    float* __restrict__ h, float* __restrict__ x,
    const float* __restrict__ aggM, const float* __restrict__ aggX,
    const float* __restrict__ cnt,
    const float* __restrict__ nW1, const float* __restrict__ nb1,
    const float* __restrict__ nW2, const float* __restrict__ nb2)
{
    int n = blockIdx.x * 256 + threadIdx.x;
    if (n >= NN) return;
    float inv = 1.0f / fmaxf(cnt[n], 1.0f);
    x[n*3+0] += aggX[n*3+0] * inv;
    x[n*3+1] += aggX[n*3+1] * inv;
    x[n*3+2] += aggX[n*3+2] * inv;

    float hv[HD], ag[HD];
    const float4* hp = (const float4*)(h + (size_t)n * HD);
    const float4* ap = (const float4*)(aggM + (size_t)n * HD);
#pragma unroll
    for (int i = 0; i < HD/4; i++) {
        float4 v = hp[i];
        hv[4*i+0] = v.x; hv[4*i+1] = v.y; hv[4*i+2] = v.z; hv[4*i+3] = v.w;
        float4 w = ap[i];
        ag[4*i+0] = w.x; ag[4*i+1] = w.y; ag[4*i+2] = w.z; ag[4*i+3] = w.w;
    }
    float u1[HD];
#pragma unroll
    for (int j = 0; j < HD; j++) u1[j] = nb1[j];
#pragma unroll
    for (int i = 0; i < HD; i++) {
        float a = hv[i];
#pragma unroll
        for (int j = 0; j < HD; j++) u1[j] = fmaf(a, nW1[i * HD + j], u1[j]);
    }
#pragma unroll
    for (int i = 0; i < HD; i++) {
        float a = ag[i];
#pragma unroll
        for (int j = 0; j < HD; j++) u1[j] = fmaf(a, nW1[(HD + i) * HD + j], u1[j]);
    }
#pragma unroll
    for (int j = 0; j < HD; j++) u1[j] = silu_f(u1[j]);
    float u2[HD];
#pragma unroll
    for (int j = 0; j < HD; j++) u2[j] = nb2[j];
#pragma unroll
    for (int i = 0; i < HD; i++) {
        float a = u1[i];
#pragma unroll
        for (int j = 0; j < HD; j++) u2[j] = fmaf(a, nW2[i * HD + j], u2[j]);
    }
    float4* ho = (float4*)(h + (size_t)n * HD);
#pragma unroll
    for (int j = 0; j < HD/4; j++)
        ho[j] = make_float4(hv[4*j+0] + u2[4*j+0], hv[4*j+1] + u2[4*j+1],
                            hv[4*j+2] + u2[4*j+2], hv[4*j+3] + u2[4*j+3]);
}

// ---------------- output projection: out = h @ Wout + bout ----------------
__global__ __launch_bounds__(256) void out_kernel(
    const float* __restrict__ h, const float* __restrict__ W,
    const float* __restrict__ b, float* __restrict__ out)
{
    int n = blockIdx.x * 256 + threadIdx.x;
    if (n >= NN) return;
    float hv[HD];
    const float4* hp = (const float4*)(h + (size_t)n * HD);
#pragma unroll
    for (int i = 0; i < HD/4; i++) {
        float4 v = hp[i];
        hv[4*i+0] = v.x; hv[4*i+1] = v.y; hv[4*i+2] = v.z; hv[4*i+3] = v.w;
    }
    float o[COUT];
#pragma unroll
    for (int j = 0; j < COUT; j++) o[j] = b[j];
#pragma unroll
    for (int i = 0; i < HD; i++) {
        float a = hv[i];
#pragma unroll
        for (int j = 0; j < COUT; j++) o[j] = fmaf(a, W[i * COUT + j], o[j]);
    }
    float4* op = (float4*)(out + (size_t)n * COUT);
#pragma unroll
    for (int j = 0; j < COUT/4; j++)
        op[j] = make_float4(o[4*j+0], o[4*j+1], o[4*j+2], o[4*j+3]);
}

extern "C" void kernel_launch(void* const* d_in, const int* in_sizes, int n_in,
                              void* d_out, int out_size, void* d_ws, size_t ws_size,
                              hipStream_t stream) {
    // setup_inputs() dict insertion order (NOT the reference() signature order):
    //  0 data, 1 pos, 2 edge_attr, 3 t, 4 row, 5 col,
    //  6 emb_in_w, 7 emb_in_b, 8 emb_out_w, 9 emb_out_b,
    // 10 edge_w1, 11 edge_b1, 12 edge_w2, 13 edge_b2,
    // 14 node_w1, 15 node_b1, 16 node_w2, 17 node_b2,
    // 18 coord_w1, 19 coord_b1, 20 coord_w2
    const float* data      = (const float*)d_in[0];
    const float* pos       = (const float*)d_in[1];
    const float* edge_attr = (const float*)d_in[2];
    const float* tptr      = (const float*)d_in[3];
    const int*   row       = (const int*)d_in[4];
    const int*   col       = (const int*)d_in[5];
    const float* emb_in_w  = (const float*)d_in[6];
    const float* emb_in_b  = (const float*)d_in[7];
    const float* emb_out_w = (const float*)d_in[8];
    const float* emb_out_b = (const float*)d_in[9];
    const float* edge_w1   = (const float*)d_in[10];
    const float* edge_b1   = (const float*)d_in[11];
    const float* edge_w2   = (const float*)d_in[12];
    const float* edge_b2   = (const float*)d_in[13];
    const float* node_w1   = (const float*)d_in[14];
    const float* node_b1   = (const float*)d_in[15];
    const float* node_w2   = (const float*)d_in[16];
    const float* node_b2   = (const float*)d_in[17];
    const float* coord_w1  = (const float*)d_in[18];
    const float* coord_b1  = (const float*)d_in[19];
    const float* coord_w2  = (const float*)d_in[20];
    float* out = (float*)d_out;

    // workspace layout (floats)
    float* ws   = (float*)d_ws;
    float* h    = ws;                  // NN*HD   = 1,600,000
    float* x    = ws + 1600000;        // NN*3    =   150,000
    float* cnt  = ws + 1750000;        // NN      =    50,000
    float* aggM = ws + 1800000;        // NN*HD   = 1,600,000
    float* aggX = ws + 3400000;        // NN*3    =   150,000  (contiguous after aggM)

    hipMemsetAsync(cnt, 0, NN * sizeof(float), stream);
    embed_kernel<<<(NN + 255) / 256, 256, 0, stream>>>(data, pos, tptr, emb_in_w, emb_in_b, h, x);
    cnt_kernel<<<(NE + 255) / 256, 256, 0, stream>>>(row, cnt);

    for (int l = 0; l < NL; l++) {
        hipMemsetAsync(aggM, 0, (size_t)(NN * HD + NN * 3) * sizeof(float), stream);
        edge_kernel<<<(NE + 255) / 256, 256, 0, stream>>>(
            h, x, edge_attr, row, col,
            edge_w1 + l * (2*HD+2) * HD, edge_b1 + l * HD,
            edge_w2 + l * HD * HD,       edge_b2 + l * HD,
            coord_w1 + l * HD * HD,      coord_b1 + l * HD,
            coord_w2 + l * HD,
            aggM, aggX);
        node_kernel<<<(NN + 255) / 256, 256, 0, stream>>>(
            h, x, aggM, aggX, cnt,
            node_w1 + l * 2 * HD * HD, node_b1 + l * HD,
            node_w2 + l * HD * HD,     node_b2 + l * HD);
    }
    out_kernel<<<(NN + 255) / 256, 256, 0, stream>>>(h, emb_out_w, emb_out_b, out);
}

// Round 3
// 790.785 us; speedup vs baseline: 7.9956x; 7.9956x over previous
//
#include <hip/hip_runtime.h>

#define NN 50000
#define NE 800000
#define CIN 64
#define COUT 64
#define HD 32
#define NL 4

__device__ __forceinline__ float silu_f(float v) {
    return v * __builtin_amdgcn_rcpf(1.0f + __expf(-v));
}

// ---------------- embed: h = [t, data] @ W + b ; x4 = [pos, 0, 0] ----------------
__global__ __launch_bounds__(256) void embed_kernel(
    const float* __restrict__ data, const float* __restrict__ pos,
    const float* __restrict__ tptr,
    const float* __restrict__ W, const float* __restrict__ b,
    float* __restrict__ h, float* __restrict__ x4)
{
    int n = blockIdx.x * 256 + threadIdx.x;
    if (n >= NN) return;
    float t = tptr[0];
    float d[CIN];
    const float4* dp = (const float4*)(data + (size_t)n * CIN);
#pragma unroll
    for (int i = 0; i < CIN / 4; i++) {
        float4 v = dp[i];
        d[4*i+0] = v.x; d[4*i+1] = v.y; d[4*i+2] = v.z; d[4*i+3] = v.w;
    }
    float acc[HD];
#pragma unroll
    for (int j = 0; j < HD; j++) acc[j] = fmaf(t, W[j], b[j]);   // row 0 of W is the t channel
#pragma unroll
    for (int i = 0; i < CIN; i++) {
        float a = d[i];
#pragma unroll
        for (int j = 0; j < HD; j++) acc[j] = fmaf(a, W[(i + 1) * HD + j], acc[j]);
    }
    float4* hp = (float4*)(h + (size_t)n * HD);
#pragma unroll
    for (int j = 0; j < HD / 4; j++)
        hp[j] = make_float4(acc[4*j], acc[4*j+1], acc[4*j+2], acc[4*j+3]);
    ((float4*)x4)[n] = make_float4(pos[n*2+0], pos[n*2+1], 0.0f, 0.0f);
}

// ---------------- sort prologue ----------------
__global__ __launch_bounds__(256) void hist_kernel(const int* __restrict__ row,
                                                   int* __restrict__ cnt)
{
    int e = blockIdx.x * 256 + threadIdx.x;
    if (e < NE) atomicAdd(&cnt[row[e]], 1);
}

// single block, 1024 threads: exclusive scan of cnt[NN] -> rowstart[NN+1]
__global__ __launch_bounds__(1024) void scan_kernel(const int* __restrict__ cnt,
                                                    int* __restrict__ rowstart)
{
    __shared__ int sdata[1024];
    __shared__ int carry;
    if (threadIdx.x == 0) carry = 0;
    __syncthreads();
    for (int base = 0; base < NN; base += 1024) {
        int i = base + (int)threadIdx.x;
        int v = (i < NN) ? cnt[i] : 0;
        sdata[threadIdx.x] = v;
        __syncthreads();
        for (int off = 1; off < 1024; off <<= 1) {
            int t = (threadIdx.x >= (unsigned)off) ? sdata[threadIdx.x - off] : 0;
            __syncthreads();
            sdata[threadIdx.x] += t;
            __syncthreads();
        }
        int incl = sdata[threadIdx.x];
        if (i < NN) rowstart[i] = carry + incl - v;
        __syncthreads();
        if (threadIdx.x == 1023) carry += sdata[1023];
        __syncthreads();
    }
    if (threadIdx.x == 0) rowstart[NN] = carry;
}

__global__ __launch_bounds__(256) void scatter_kernel(
    const int* __restrict__ row, const int* __restrict__ col,
    const float* __restrict__ edge_attr,
    const int* __restrict__ rowstart, int* __restrict__ cursor,
    int* __restrict__ srow, int* __restrict__ scol, float* __restrict__ sea)
{
    int e = blockIdx.x * 256 + threadIdx.x;
    if (e >= NE) return;
    int r = row[e];
    int p = rowstart[r] + atomicAdd(&cursor[r], 1);
    srow[p] = r;
    scol[p] = col[e];
    sea[p]  = edge_attr[e];
}

// ---------------- per-layer: Hr = h @ W1[0:32], Hc = h @ W1[32:64] ----------------
__global__ __launch_bounds__(256) void prenode_kernel(
    const float* __restrict__ h, const float* __restrict__ eW1,
    float* __restrict__ Hr, float* __restrict__ Hc)
{
    int n = blockIdx.x * 256 + threadIdx.x;
    if (n >= NN) return;
    float hv[HD];
    const float4* hp = (const float4*)(h + (size_t)n * HD);
#pragma unroll
    for (int i = 0; i < HD/4; i++) {
        float4 v = hp[i];
        hv[4*i+0] = v.x; hv[4*i+1] = v.y; hv[4*i+2] = v.z; hv[4*i+3] = v.w;
    }
    float a[HD];
#pragma unroll
    for (int j = 0; j < HD; j++) a[j] = 0.0f;
#pragma unroll
    for (int i = 0; i < HD; i++) {
        float x = hv[i];
#pragma unroll
        for (int j = 0; j < HD; j++) a[j] = fmaf(x, eW1[i * HD + j], a[j]);
    }
    float4* op = (float4*)(Hr + (size_t)n * HD);
#pragma unroll
    for (int j = 0; j < HD/4; j++)
        op[j] = make_float4(a[4*j], a[4*j+1], a[4*j+2], a[4*j+3]);
#pragma unroll
    for (int j = 0; j < HD; j++) a[j] = 0.0f;
#pragma unroll
    for (int i = 0; i < HD; i++) {
        float x = hv[i];
#pragma unroll
        for (int j = 0; j < HD; j++) a[j] = fmaf(x, eW1[(HD + i) * HD + j], a[j]);
    }
    op = (float4*)(Hc + (size_t)n * HD);
#pragma unroll
    for (int j = 0; j < HD/4; j++)
        op[j] = make_float4(a[4*j], a[4*j+1], a[4*j+2], a[4*j+3]);
}

// ---------------- edge kernel (sorted, no atomics): writes mbuf + xbuf ----------------
__global__ __launch_bounds__(256) void edge_sorted_kernel(
    const float* __restrict__ x4,
    const int* __restrict__ srow, const int* __restrict__ scol,
    const float* __restrict__ sea,
    const float* __restrict__ Hr, const float* __restrict__ Hc,
    const float* __restrict__ eW1, const float* __restrict__ eb1,
    const float* __restrict__ eW2, const float* __restrict__ eb2,
    const float* __restrict__ cW1, const float* __restrict__ cb1,
    const float* __restrict__ cW2,
    float* __restrict__ mbuf, float* __restrict__ xbuf4)
{
    int s = blockIdx.x * 256 + threadIdx.x;   // NE is an exact multiple of 256
    int r = srow[s], c = scol[s];
    float4 xr = ((const float4*)x4)[r];
    float4 xc = ((const float4*)x4)[c];
    float d0 = xr.x - xc.x, d1 = xr.y - xc.y, d2 = xr.z - xc.z;
    float radial = d0*d0 + d1*d1 + d2*d2;
    float ea = sea[s];

    const float4* hr = (const float4*)(Hr + (size_t)r * HD);
    const float4* hc = (const float4*)(Hc + (size_t)c * HD);
    float t1[HD];
#pragma unroll
    for (int i = 0; i < HD/4; i++) {
        float4 a = hr[i];
        float4 b = hc[i];
        int k = 4*i;
        t1[k+0] = a.x + b.x + radial*eW1[64*HD+k+0] + ea*eW1[65*HD+k+0] + eb1[k+0];
        t1[k+1] = a.y + b.y + radial*eW1[64*HD+k+1] + ea*eW1[65*HD+k+1] + eb1[k+1];
        t1[k+2] = a.z + b.z + radial*eW1[64*HD+k+2] + ea*eW1[65*HD+k+2] + eb1[k+2];
        t1[k+3] = a.w + b.w + radial*eW1[64*HD+k+3] + ea*eW1[65*HD+k+3] + eb1[k+3];
    }
#pragma unroll
    for (int j = 0; j < HD; j++) t1[j] = silu_f(t1[j]);

    // GEMM2: 32 -> 32, silu -> m
    float m[HD];
#pragma unroll
    for (int j = 0; j < HD; j++) m[j] = eb2[j];
#pragma unroll
    for (int i = 0; i < HD; i++) {
        float a = t1[i];
#pragma unroll
        for (int j = 0; j < HD; j++) m[j] = fmaf(a, eW2[i * HD + j], m[j]);
    }
#pragma unroll
    for (int j = 0; j < HD; j++) m[j] = silu_f(m[j]);

    // store m early (coalesced 128B per thread)
    float4* mp = (float4*)(mbuf + (size_t)s * HD);
#pragma unroll
    for (int i = 0; i < HD/4; i++)
        mp[i] = make_float4(m[4*i], m[4*i+1], m[4*i+2], m[4*i+3]);

    // coord MLP: m -> 32 (silu) -> 1
    float c1[HD];
#pragma unroll
    for (int j = 0; j < HD; j++) c1[j] = cb1[j];
#pragma unroll
    for (int i = 0; i < HD; i++) {
        float a = m[i];
#pragma unroll
        for (int j = 0; j < HD; j++) c1[j] = fmaf(a, cW1[i * HD + j], c1[j]);
    }
    float phi = 0.0f;
#pragma unroll
    for (int j = 0; j < HD; j++) phi = fmaf(silu_f(c1[j]), cW2[j], phi);

    ((float4*)xbuf4)[s] = make_float4(d0*phi, d1*phi, d2*phi, 0.0f);
}

// ---------------- fused node kernel: CSR agg + x update + node MLP ----------------
__global__ __launch_bounds__(256) void node_fused_kernel(
    float* __restrict__ h, float* __restrict__ x4,
    const float* __restrict__ mbuf, const float* __restrict__ xbuf4,
    const int* __restrict__ rowstart,
    const float* __restrict__ nW1, const float* __restrict__ nb1,
    const float* __restrict__ nW2, const float* __restrict__ nb2)
{
    __shared__ float sIn[8][2*HD];
    __shared__ float sU[8][HD];
    int local = threadIdx.x >> 5;
    int ch    = threadIdx.x & 31;
    int n = blockIdx.x * 8 + local;          // NN == 6250*8, exact
    int s0 = rowstart[n], s1 = rowstart[n+1];

    float am = 0.0f, ax = 0.0f;
    for (int s = s0; s < s1; s++) {
        am += mbuf[(size_t)s * HD + ch];
        if (ch < 4) ax += xbuf4[(size_t)s * 4 + ch];
    }
    float hv = h[(size_t)n * HD + ch];
    sIn[local][ch]      = hv;
    sIn[local][HD + ch] = am;
    if (ch < 3) {
        float cf = (float)(s1 - s0);
        if (cf < 1.0f) cf = 1.0f;
        x4[(size_t)n * 4 + ch] += ax / cf;
    }
    __syncthreads();
    float u1 = nb1[ch];
#pragma unroll 8
    for (int i = 0; i < 2*HD; i++) u1 = fmaf(sIn[local][i], nW1[i * HD + ch], u1);
    u1 = silu_f(u1);
    sU[local][ch] = u1;
    __syncthreads();
    float u2 = nb2[ch];
#pragma unroll 8
    for (int i = 0; i < HD; i++) u2 = fmaf(sU[local][i], nW2[i * HD + ch], u2);
    h[(size_t)n * HD + ch] = hv + u2;
}

// ---------------- output projection: out = h @ Wout + bout ----------------
__global__ __launch_bounds__(256) void out_kernel(
    const float* __restrict__ h, const float* __restrict__ W,
    const float* __restrict__ b, float* __restrict__ out)
{
    int n = blockIdx.x * 256 + threadIdx.x;
    if (n >= NN) return;
    float hv[HD];
    const float4* hp = (const float4*)(h + (size_t)n * HD);
#pragma unroll
    for (int i = 0; i < HD/4; i++) {
        float4 v = hp[i];
        hv[4*i+0] = v.x; hv[4*i+1] = v.y; hv[4*i+2] = v.z; hv[4*i+3] = v.w;
    }
    float o[COUT];
#pragma unroll
    for (int j = 0; j < COUT; j++) o[j] = b[j];
#pragma unroll
    for (int i = 0; i < HD; i++) {
        float a = hv[i];
#pragma unroll
        for (int j = 0; j < COUT; j++) o[j] = fmaf(a, W[i * COUT + j], o[j]);
    }
    float4* op = (float4*)(out + (size_t)n * COUT);
#pragma unroll
    for (int j = 0; j < COUT/4; j++)
        op[j] = make_float4(o[4*j], o[4*j+1], o[4*j+2], o[4*j+3]);
}

// ================= fallback (atomic) path, as in the passing round-1 kernel ========
__global__ __launch_bounds__(256) void cntf_kernel(const int* __restrict__ row,
                                                   float* __restrict__ cnt)
{
    int e = blockIdx.x * 256 + threadIdx.x;
    if (e < NE) atomicAdd(&cnt[row[e]], 1.0f);
}

__global__ __launch_bounds__(256) void edge_atomic_kernel(
    const float* __restrict__ h, const float* __restrict__ x4,
    const float* __restrict__ edge_attr,
    const int* __restrict__ row, const int* __restrict__ col,
    const float* __restrict__ eW1, const float* __restrict__ eb1,
    const float* __restrict__ eW2, const float* __restrict__ eb2,
    const float* __restrict__ cW1, const float* __restrict__ cb1,
    const float* __restrict__ cW2,
    float* __restrict__ aggM, float* __restrict__ aggX4)
{
    int e = blockIdx.x * 256 + threadIdx.x;
    if (e >= NE) return;
    int r = row[e], c = col[e];
    float4 xr = ((const float4*)x4)[r];
    float4 xc = ((const float4*)x4)[c];
    float d0 = xr.x - xc.x, d1 = xr.y - xc.y, d2 = xr.z - xc.z;
    float radial = d0*d0 + d1*d1 + d2*d2;

    float ein[2*HD+2];
    const float4* hr = (const float4*)(h + (size_t)r * HD);
    const float4* hc = (const float4*)(h + (size_t)c * HD);
#pragma unroll
    for (int i = 0; i < HD/4; i++) {
        float4 v = hr[i];
        ein[4*i+0] = v.x; ein[4*i+1] = v.y; ein[4*i+2] = v.z; ein[4*i+3] = v.w;
    }
#pragma unroll
    for (int i = 0; i < HD/4; i++) {
        float4 v = hc[i];
        ein[HD+4*i+0] = v.x; ein[HD+4*i+1] = v.y; ein[HD+4*i+2] = v.z; ein[HD+4*i+3] = v.w;
    }
    ein[2*HD+0] = radial;
    ein[2*HD+1] = edge_attr[e];

    float t1[HD];
#pragma unroll
    for (int j = 0; j < HD; j++) t1[j] = eb1[j];
#pragma unroll
    for (int i = 0; i < 2*HD+2; i++) {
        float a = ein[i];
#pragma unroll
        for (int j = 0; j < HD; j++) t1[j] = fmaf(a, eW1[i * HD + j], t1[j]);
    }
#pragma unroll
    for (int j = 0; j < HD; j++) t1[j] = silu_f(t1[j]);

    float m[HD];
#pragma unroll
    for (int j = 0; j < HD; j++) m[j] = eb2[j];
#pragma unroll
    for (int i = 0; i < HD; i++) {
        float a = t1[i];
#pragma unroll
        for (int j = 0; j < HD; j++) m[j] = fmaf(a, eW2[i * HD + j], m[j]);
    }
#pragma unroll
    for (int j = 0; j < HD; j++) m[j] = silu_f(m[j]);

    float c1[HD];
#pragma unroll
    for (int j = 0; j < HD; j++) c1[j] = cb1[j];
#pragma unroll
    for (int i = 0; i < HD; i++) {
        float a = m[i];
#pragma unroll
        for (int j = 0; j < HD; j++) c1[j] = fmaf(a, cW1[i * HD + j], c1[j]);
    }
    float phi = 0.0f;
#pragma unroll
    for (int j = 0; j < HD; j++) phi = fmaf(silu_f(c1[j]), cW2[j], phi);

    atomicAdd(&aggX4[(size_t)r*4+0], d0 * phi);
    atomicAdd(&aggX4[(size_t)r*4+1], d1 * phi);
    atomicAdd(&aggX4[(size_t)r*4+2], d2 * phi);
#pragma unroll
    for (int j = 0; j < HD; j++) atomicAdd(&aggM[(size_t)r * HD + j], m[j]);
}

__global__ __launch_bounds__(256) void node_plain_kernel(
    float* __restrict__ h, float* __restrict__ x4,
    const float* __restrict__ aggM, const float* __restrict__ aggX4,
    const float* __restrict__ cnt,
    const float* __restrict__ nW1, const float* __restrict__ nb1,
    const float* __restrict__ nW2, const float* __restrict__ nb2)
{
    int n = blockIdx.x * 256 + threadIdx.x;
    if (n >= NN) return;
    float inv = 1.0f / fmaxf(cnt[n], 1.0f);
    x4[n*4+0] += aggX4[n*4+0] * inv;
    x4[n*4+1] += aggX4[n*4+1] * inv;
    x4[n*4+2] += aggX4[n*4+2] * inv;

    float hv[HD], ag[HD];
    const float4* hp = (const float4*)(h + (size_t)n * HD);
    const float4* ap = (const float4*)(aggM + (size_t)n * HD);
#pragma unroll
    for (int i = 0; i < HD/4; i++) {
        float4 v = hp[i];
        hv[4*i+0] = v.x; hv[4*i+1] = v.y; hv[4*i+2] = v.z; hv[4*i+3] = v.w;
        float4 w = ap[i];
        ag[4*i+0] = w.x; ag[4*i+1] = w.y; ag[4*i+2] = w.z; ag[4*i+3] = w.w;
    }
    float u1[HD];
#pragma unroll
    for (int j = 0; j < HD; j++) u1[j] = nb1[j];
#pragma unroll
    for (int i = 0; i < HD; i++) {
        float a = hv[i];
#pragma unroll
        for (int j = 0; j < HD; j++) u1[j] = fmaf(a, nW1[i * HD + j], u1[j]);
    }
#pragma unroll
    for (int i = 0; i < HD; i++) {
        float a = ag[i];
#pragma unroll
        for (int j = 0; j < HD; j++) u1[j] = fmaf(a, nW1[(HD + i) * HD + j], u1[j]);
    }
#pragma unroll
    for (int j = 0; j < HD; j++) u1[j] = silu_f(u1[j]);
    float u2[HD];
#pragma unroll
    for (int j = 0; j < HD; j++) u2[j] = nb2[j];
#pragma unroll
    for (int i = 0; i < HD; i++) {
        float a = u1[i];
#pragma unroll
        for (int j = 0; j < HD; j++) u2[j] = fmaf(a, nW2[i * HD + j], u2[j]);
    }
    float4* ho = (float4*)(h + (size_t)n * HD);
#pragma unroll
    for (int j = 0; j < HD/4; j++)
        ho[j] = make_float4(hv[4*j+0] + u2[4*j+0], hv[4*j+1] + u2[4*j+1],
                            hv[4*j+2] + u2[4*j+2], hv[4*j+3] + u2[4*j+3]);
}

extern "C" void kernel_launch(void* const* d_in, const int* in_sizes, int n_in,
                              void* d_out, int out_size, void* d_ws, size_t ws_size,
                              hipStream_t stream) {
    // setup_inputs() dict insertion order:
    //  0 data, 1 pos, 2 edge_attr, 3 t, 4 row, 5 col,
    //  6 emb_in_w, 7 emb_in_b, 8 emb_out_w, 9 emb_out_b,
    // 10 edge_w1, 11 edge_b1, 12 edge_w2, 13 edge_b2,
    // 14 node_w1, 15 node_b1, 16 node_w2, 17 node_b2,
    // 18 coord_w1, 19 coord_b1, 20 coord_w2
    const float* data      = (const float*)d_in[0];
    const float* pos       = (const float*)d_in[1];
    const float* edge_attr = (const float*)d_in[2];
    const float* tptr      = (const float*)d_in[3];
    const int*   row       = (const int*)d_in[4];
    const int*   col       = (const int*)d_in[5];
    const float* emb_in_w  = (const float*)d_in[6];
    const float* emb_in_b  = (const float*)d_in[7];
    const float* emb_out_w = (const float*)d_in[8];
    const float* emb_out_b = (const float*)d_in[9];
    const float* edge_w1   = (const float*)d_in[10];
    const float* edge_b1   = (const float*)d_in[11];
    const float* edge_w2   = (const float*)d_in[12];
    const float* edge_b2   = (const float*)d_in[13];
    const float* node_w1   = (const float*)d_in[14];
    const float* node_b1   = (const float*)d_in[15];
    const float* node_w2   = (const float*)d_in[16];
    const float* node_b2   = (const float*)d_in[17];
    const float* coord_w1  = (const float*)d_in[18];
    const float* coord_b1  = (const float*)d_in[19];
    const float* coord_w2  = (const float*)d_in[20];
    float* out = (float*)d_out;

    float* ws = (float*)d_ws;

    // ---- sorted-path workspace layout (element offsets, all 16B-aligned where needed)
    const size_t O_h        = 0;          // NN*32 = 1,600,000
    const size_t O_x4       = 1600000;    // NN*4  =   200,000
    const size_t O_Hr       = 1800000;    // NN*32 = 1,600,000
    const size_t O_Hc       = 3400000;    // NN*32 = 1,600,000
    const size_t O_sea      = 5000000;    // NE    =   800,000
    const size_t O_rowstart = 5800000;    // NN+1 ints
    const size_t O_cursor   = 5850004;    // NN ints
    const size_t O_srow     = 5900004;    // NE ints
    const size_t O_scol     = 6700004;    // NE ints
    const size_t O_mbuf     = 7500004;    // NE*32 = 25,600,000
    const size_t O_xbuf     = 33100004;   // NE*4  = 3,200,000
    const size_t TOT_SORTED = 36300004;   // elements (~145.2 MB)

    if (ws_size >= TOT_SORTED * 4ull) {
        float* h    = ws + O_h;
        float* x4   = ws + O_x4;
        float* Hr   = ws + O_Hr;
        float* Hc   = ws + O_Hc;
        float* sea  = ws + O_sea;
        int* rowstart = (int*)(ws + O_rowstart);
        int* cursor   = (int*)(ws + O_cursor);
        int* srow     = (int*)(ws + O_srow);
        int* scol     = (int*)(ws + O_scol);
        float* mbuf   = ws + O_mbuf;
        float* xbuf4  = ws + O_xbuf;

        hipMemsetAsync(cursor, 0, NN * sizeof(int), stream);
        embed_kernel<<<(NN + 255) / 256, 256, 0, stream>>>(data, pos, tptr, emb_in_w, emb_in_b, h, x4);
        hist_kernel<<<NE / 256, 256, 0, stream>>>(row, cursor);
        scan_kernel<<<1, 1024, 0, stream>>>(cursor, rowstart);
        hipMemsetAsync(cursor, 0, NN * sizeof(int), stream);
        scatter_kernel<<<NE / 256, 256, 0, stream>>>(row, col, edge_attr, rowstart, cursor, srow, scol, sea);

        for (int l = 0; l < NL; l++) {
            prenode_kernel<<<(NN + 255) / 256, 256, 0, stream>>>(h, edge_w1 + l * (2*HD+2) * HD, Hr, Hc);
            edge_sorted_kernel<<<NE / 256, 256, 0, stream>>>(
                x4, srow, scol, sea, Hr, Hc,
                edge_w1 + l * (2*HD+2) * HD, edge_b1 + l * HD,
                edge_w2 + l * HD * HD,       edge_b2 + l * HD,
                coord_w1 + l * HD * HD,      coord_b1 + l * HD,
                coord_w2 + l * HD,
                mbuf, xbuf4);
            node_fused_kernel<<<NN / 8, 256, 0, stream>>>(
                h, x4, mbuf, xbuf4, rowstart,
                node_w1 + l * 2 * HD * HD, node_b1 + l * HD,
                node_w2 + l * HD * HD,     node_b2 + l * HD);
        }
        out_kernel<<<(NN + 255) / 256, 256, 0, stream>>>(h, emb_out_w, emb_out_b, out);
    } else {
        // ---- fallback: atomic path (~14.6 MB of ws)
        float* h     = ws;                 // 1,600,000
        float* x4    = ws + 1600000;       //   200,000
        float* cntf  = ws + 1800000;       //    50,000
        float* aggM  = ws + 1850000;       // 1,600,000
        float* aggX4 = ws + 3450000;       //   200,000 (contiguous after aggM)

        hipMemsetAsync(cntf, 0, NN * sizeof(float), stream);
        embed_kernel<<<(NN + 255) / 256, 256, 0, stream>>>(data, pos, tptr, emb_in_w, emb_in_b, h, x4);
        cntf_kernel<<<NE / 256, 256, 0, stream>>>(row, cntf);

        for (int l = 0; l < NL; l++) {
            hipMemsetAsync(aggM, 0, (size_t)(NN * HD + NN * 4) * sizeof(float), stream);
            edge_atomic_kernel<<<NE / 256, 256, 0, stream>>>(
                h, x4, edge_attr, row, col,
                edge_w1 + l * (2*HD+2) * HD, edge_b1 + l * HD,
                edge_w2 + l * HD * HD,       edge_b2 + l * HD,
                coord_w1 + l * HD * HD,      coord_b1 + l * HD,
                coord_w2 + l * HD,
                aggM, aggX4);
            node_plain_kernel<<<(NN + 255) / 256, 256, 0, stream>>>(
                h, x4, aggM, aggX4, cntf,
                node_w1 + l * 2 * HD * HD, node_b1 + l * HD,
                node_w2 + l * HD * HD,     node_b2 + l * HD);
        }
        out_kernel<<<(NN + 255) / 256, 256, 0, stream>>>(h, emb_out_w, emb_out_b, out);
    }
}

// Round 4
// 596.272 us; speedup vs baseline: 10.6039x; 1.3262x over previous
//
#include <hip/hip_runtime.h>

#define NN 50000
#define NE 800000
#define CIN 64
#define COUT 64
#define HD 32
#define NL 4
#define NB_SCAN 49   // ceil(NN/1024)

__device__ __forceinline__ float silu_f(float v) {
    return v * __builtin_amdgcn_rcpf(1.0f + __expf(-v));
}

// ---------------- embed: h = [t, data] @ W + b ; x4 = [pos,0,0]; Hr/Hc for layer 0 ----
__global__ __launch_bounds__(256) void embed_kernel(
    const float* __restrict__ data, const float* __restrict__ pos,
    const float* __restrict__ tptr,
    const float* __restrict__ W, const float* __restrict__ b,
    const float* __restrict__ eW1_0,
    float* __restrict__ h, float* __restrict__ x4,
    float* __restrict__ Hr, float* __restrict__ Hc)
{
    int n = blockIdx.x * 256 + threadIdx.x;
    if (n >= NN) return;
    float t = tptr[0];
    float d[CIN];
    const float4* dp = (const float4*)(data + (size_t)n * CIN);
#pragma unroll
    for (int i = 0; i < CIN / 4; i++) {
        float4 v = dp[i];
        d[4*i+0] = v.x; d[4*i+1] = v.y; d[4*i+2] = v.z; d[4*i+3] = v.w;
    }
    float acc[HD];
#pragma unroll
    for (int j = 0; j < HD; j++) acc[j] = fmaf(t, W[j], b[j]);   // row 0 = t channel
#pragma unroll
    for (int i = 0; i < CIN; i++) {
        float a = d[i];
#pragma unroll
        for (int j = 0; j < HD; j++) acc[j] = fmaf(a, W[(i + 1) * HD + j], acc[j]);
    }
    float4* hp = (float4*)(h + (size_t)n * HD);
#pragma unroll
    for (int j = 0; j < HD / 4; j++)
        hp[j] = make_float4(acc[4*j], acc[4*j+1], acc[4*j+2], acc[4*j+3]);
    ((float4*)x4)[n] = make_float4(pos[n*2+0], pos[n*2+1], 0.0f, 0.0f);

    // Hr = h @ eW1_0[0:32], Hc = h @ eW1_0[32:64]
    float a1[HD], a2[HD];
#pragma unroll
    for (int j = 0; j < HD; j++) { a1[j] = 0.0f; a2[j] = 0.0f; }
#pragma unroll
    for (int i = 0; i < HD; i++) {
        float z = acc[i];
#pragma unroll
        for (int j = 0; j < HD; j++) {
            a1[j] = fmaf(z, eW1_0[i * HD + j], a1[j]);
            a2[j] = fmaf(z, eW1_0[(HD + i) * HD + j], a2[j]);
        }
    }
    float4* rp = (float4*)(Hr + (size_t)n * HD);
    float4* cp = (float4*)(Hc + (size_t)n * HD);
#pragma unroll
    for (int j = 0; j < HD/4; j++) {
        rp[j] = make_float4(a1[4*j], a1[4*j+1], a1[4*j+2], a1[4*j+3]);
        cp[j] = make_float4(a2[4*j], a2[4*j+1], a2[4*j+2], a2[4*j+3]);
    }
}

// ---------------- sort prologue ----------------
__global__ __launch_bounds__(256) void hist_kernel(const int* __restrict__ row,
                                                   int* __restrict__ cnt)
{
    int e = blockIdx.x * 256 + threadIdx.x;
    if (e < NE) atomicAdd(&cnt[row[e]], 1);
}

// hierarchical scan: A = per-block scan, B = scan of block sums (1 wave), C = add offsets
__global__ __launch_bounds__(1024) void scanA_kernel(const int* __restrict__ cnt,
                                                     int* __restrict__ rowstart,
                                                     int* __restrict__ bsum)
{
    __shared__ int sd[1024];
    int i = blockIdx.x * 1024 + threadIdx.x;
    int v = (i < NN) ? cnt[i] : 0;
    sd[threadIdx.x] = v;
    __syncthreads();
    for (int off = 1; off < 1024; off <<= 1) {
        int t = (threadIdx.x >= (unsigned)off) ? sd[threadIdx.x - off] : 0;
        __syncthreads();
        sd[threadIdx.x] += t;
        __syncthreads();
    }
    if (i < NN) rowstart[i] = sd[threadIdx.x] - v;   // exclusive within block
    if (threadIdx.x == 1023) bsum[blockIdx.x] = sd[1023];
}

__global__ __launch_bounds__(64) void scanB_kernel(const int* __restrict__ bsum,
                                                   int* __restrict__ boff,
                                                   int* __restrict__ rowstart)
{
    int lane = threadIdx.x;
    int v = (lane < NB_SCAN) ? bsum[lane] : 0;
    int x = v;
    for (int off = 1; off < 64; off <<= 1) {
        int y = __shfl_up(x, off);
        if (lane >= off) x += y;
    }
    if (lane < NB_SCAN) boff[lane] = x - v;          // exclusive
    if (lane == 63) rowstart[NN] = x;                // grand total (= NE)
}

__global__ __launch_bounds__(1024) void scanC_kernel(int* __restrict__ rowstart,
                                                     const int* __restrict__ boff)
{
    int i = blockIdx.x * 1024 + threadIdx.x;
    if (i < NN) rowstart[i] += boff[blockIdx.x];
}

__global__ __launch_bounds__(256) void scatter_kernel(
    const int* __restrict__ row, const int* __restrict__ col,
    const float* __restrict__ edge_attr,
    const int* __restrict__ rowstart, int* __restrict__ cursor,
    int* __restrict__ srow, int* __restrict__ scol, float* __restrict__ sea)
{
    int e = blockIdx.x * 256 + threadIdx.x;
    if (e >= NE) return;
    int r = row[e];
    int p = rowstart[r] + atomicAdd(&cursor[r], 1);
    srow[p] = r;
    scol[p] = col[e];
    sea[p]  = edge_attr[e];
}

// ------- fused edge kernel: MLPs + block-segmented aggregation (no mbuf) -------
__global__ __launch_bounds__(256) void edge_fused_kernel(
    const float* __restrict__ x4,
    const int* __restrict__ srow, const int* __restrict__ scol,
    const float* __restrict__ sea,
    const float* __restrict__ Hr, const float* __restrict__ Hc,
    const float* __restrict__ eW1, const float* __restrict__ eb1,
    const float* __restrict__ eW2, const float* __restrict__ eb2,
    const float* __restrict__ cW1, const float* __restrict__ cb1,
    const float* __restrict__ cW2,
    const int* __restrict__ rowstart,
    float* __restrict__ aggM, float* __restrict__ aggX4)
{
    __shared__ float sm[256][HD + 1];   // +1 pad: conflict-free row writes & col reads
    __shared__ float sx[256][5];        // 5 coprime 32
    __shared__ int snf, snl;
    int tid = threadIdx.x;
    int s_base = blockIdx.x * 256;
    int s = s_base + tid;               // NE % 256 == 0
    int r = srow[s], c = scol[s];
    if (tid == 0)   snf = r;
    if (tid == 255) snl = r;

    float4 xr = ((const float4*)x4)[r];
    float4 xc = ((const float4*)x4)[c];
    float d0 = xr.x - xc.x, d1 = xr.y - xc.y, d2 = xr.z - xc.z;
    float radial = d0*d0 + d1*d1 + d2*d2;
    float ea = sea[s];

    const float4* hr = (const float4*)(Hr + (size_t)r * HD);
    const float4* hc = (const float4*)(Hc + (size_t)c * HD);
    float t1[HD];
#pragma unroll
    for (int i = 0; i < HD/4; i++) {
        float4 a = hr[i];
        float4 b = hc[i];
        int k = 4*i;
        t1[k+0] = a.x + b.x + radial*eW1[64*HD+k+0] + ea*eW1[65*HD+k+0] + eb1[k+0];
        t1[k+1] = a.y + b.y + radial*eW1[64*HD+k+1] + ea*eW1[65*HD+k+1] + eb1[k+1];
        t1[k+2] = a.z + b.z + radial*eW1[64*HD+k+2] + ea*eW1[65*HD+k+2] + eb1[k+2];
        t1[k+3] = a.w + b.w + radial*eW1[64*HD+k+3] + ea*eW1[65*HD+k+3] + eb1[k+3];
    }
#pragma unroll
    for (int j = 0; j < HD; j++) t1[j] = silu_f(t1[j]);

    // GEMM2: 32 -> 32, silu -> m
    float m[HD];
#pragma unroll
    for (int j = 0; j < HD; j++) m[j] = eb2[j];
#pragma unroll
    for (int i = 0; i < HD; i++) {
        float a = t1[i];
#pragma unroll
        for (int j = 0; j < HD; j++) m[j] = fmaf(a, eW2[i * HD + j], m[j]);
    }
#pragma unroll
    for (int j = 0; j < HD; j++) m[j] = silu_f(m[j]);

    // coord MLP: m -> 32 (silu) -> 1
    float c1[HD];
#pragma unroll
    for (int j = 0; j < HD; j++) c1[j] = cb1[j];
#pragma unroll
    for (int i = 0; i < HD; i++) {
        float a = m[i];
#pragma unroll
        for (int j = 0; j < HD; j++) c1[j] = fmaf(a, cW1[i * HD + j], c1[j]);
    }
    float phi = 0.0f;
#pragma unroll
    for (int j = 0; j < HD; j++) phi = fmaf(silu_f(c1[j]), cW2[j], phi);

    // stage into LDS
#pragma unroll
    for (int j = 0; j < HD; j++) sm[tid][j] = m[j];
    sx[tid][0] = d0 * phi; sx[tid][1] = d1 * phi; sx[tid][2] = d2 * phi;
    __syncthreads();

    // block-segmented reduction: 8 lane-groups, each group owns channel ch for nodes nf+g, nf+g+8, ...
    int g = tid >> 5, ch = tid & 31;
    int nf = snf, nl = snl;
    for (int node = nf + g; node <= nl; node += 8) {
        int lo = rowstart[node], hi = rowstart[node + 1];
        int clo = lo - s_base; if (clo < 0) clo = 0;
        int chi = hi - s_base; if (chi > 256) chi = 256;
        if (chi <= clo) continue;                       // zero-degree node in range
        float am = 0.0f;
        for (int j = clo; j < chi; j++) am += sm[j][ch];
        bool interior = (lo >= s_base) && (hi <= s_base + 256);
        if (interior) aggM[(size_t)node * HD + ch] = am;
        else          atomicAdd(&aggM[(size_t)node * HD + ch], am);
        if (ch < 3) {
            float ax = 0.0f;
            for (int j = clo; j < chi; j++) ax += sx[j][ch];
            if (interior) aggX4[(size_t)node * 4 + ch] = ax;
            else          atomicAdd(&aggX4[(size_t)node * 4 + ch], ax);
        }
    }
}

// ------- node update (+ fused Hr/Hc for next layer) -------
__global__ __launch_bounds__(256) void node_fused_kernel(
    float* __restrict__ h, float* __restrict__ x4,
    const float* __restrict__ aggM, const float* __restrict__ aggX4,
    const int* __restrict__ rowstart,
    const float* __restrict__ nW1, const float* __restrict__ nb1,
    const float* __restrict__ nW2, const float* __restrict__ nb2,
    const float* __restrict__ eW1n,   // next layer edge_w1, or nullptr on last layer
    float* __restrict__ Hr, float* __restrict__ Hc)
{
    __shared__ float sIn[8][2*HD];
    __shared__ float sU[8][HD];
    __shared__ float sH[8][HD];
    int local = threadIdx.x >> 5;
    int ch    = threadIdx.x & 31;
    int n = blockIdx.x * 8 + local;          // NN == 6250*8, exact
    float hv = h[(size_t)n * HD + ch];
    float am = aggM[(size_t)n * HD + ch];
    sIn[local][ch]      = hv;
    sIn[local][HD + ch] = am;
    if (ch < 3) {
        int cnt = rowstart[n + 1] - rowstart[n];
        float cf = (cnt < 1) ? 1.0f : (float)cnt;
        x4[(size_t)n * 4 + ch] += aggX4[(size_t)n * 4 + ch] / cf;
    }
    __syncthreads();
    float u1 = nb1[ch];
#pragma unroll 8
    for (int i = 0; i < 2*HD; i++) u1 = fmaf(sIn[local][i], nW1[i * HD + ch], u1);
    u1 = silu_f(u1);
    sU[local][ch] = u1;
    __syncthreads();
    float u2 = nb2[ch];
#pragma unroll 8
    for (int i = 0; i < HD; i++) u2 = fmaf(sU[local][i], nW2[i * HD + ch], u2);
    float hn = hv + u2;
    h[(size_t)n * HD + ch] = hn;

    if (eW1n != nullptr) {
        sH[local][ch] = hn;
        __syncthreads();
        float a = 0.0f, b = 0.0f;
#pragma unroll 8
        for (int i = 0; i < HD; i++) {
            float z = sH[local][i];
            a = fmaf(z, eW1n[i * HD + ch], a);
            b = fmaf(z, eW1n[(HD + i) * HD + ch], b);
        }
        Hr[(size_t)n * HD + ch] = a;
        Hc[(size_t)n * HD + ch] = b;
    }
}

// ---------------- output projection: out = h @ Wout + bout ----------------
__global__ __launch_bounds__(256) void out_kernel(
    const float* __restrict__ h, const float* __restrict__ W,
    const float* __restrict__ b, float* __restrict__ out)
{
    int n = blockIdx.x * 256 + threadIdx.x;
    if (n >= NN) return;
    float hv[HD];
    const float4* hp = (const float4*)(h + (size_t)n * HD);
#pragma unroll
    for (int i = 0; i < HD/4; i++) {
        float4 v = hp[i];
        hv[4*i+0] = v.x; hv[4*i+1] = v.y; hv[4*i+2] = v.z; hv[4*i+3] = v.w;
    }
    float o[COUT];
#pragma unroll
    for (int j = 0; j < COUT; j++) o[j] = b[j];
#pragma unroll
    for (int i = 0; i < HD; i++) {
        float a = hv[i];
#pragma unroll
        for (int j = 0; j < COUT; j++) o[j] = fmaf(a, W[i * COUT + j], o[j]);
    }
    float4* op = (float4*)(out + (size_t)n * COUT);
#pragma unroll
    for (int j = 0; j < COUT/4; j++)
        op[j] = make_float4(o[4*j], o[4*j+1], o[4*j+2], o[4*j+3]);
}

extern "C" void kernel_launch(void* const* d_in, const int* in_sizes, int n_in,
                              void* d_out, int out_size, void* d_ws, size_t ws_size,
                              hipStream_t stream) {
    // setup_inputs() dict insertion order:
    //  0 data, 1 pos, 2 edge_attr, 3 t, 4 row, 5 col,
    //  6 emb_in_w, 7 emb_in_b, 8 emb_out_w, 9 emb_out_b,
    // 10 edge_w1, 11 edge_b1, 12 edge_w2, 13 edge_b2,
    // 14 node_w1, 15 node_b1, 16 node_w2, 17 node_b2,
    // 18 coord_w1, 19 coord_b1, 20 coord_w2
    const float* data      = (const float*)d_in[0];
    const float* pos       = (const float*)d_in[1];
    const float* edge_attr = (const float*)d_in[2];
    const float* tptr      = (const float*)d_in[3];
    const int*   row       = (const int*)d_in[4];
    const int*   col       = (const int*)d_in[5];
    const float* emb_in_w  = (const float*)d_in[6];
    const float* emb_in_b  = (const float*)d_in[7];
    const float* emb_out_w = (const float*)d_in[8];
    const float* emb_out_b = (const float*)d_in[9];
    const float* edge_w1   = (const float*)d_in[10];
    const float* edge_b1   = (const float*)d_in[11];
    const float* edge_w2   = (const float*)d_in[12];
    const float* edge_b2   = (const float*)d_in[13];
    const float* node_w1   = (const float*)d_in[14];
    const float* node_b1   = (const float*)d_in[15];
    const float* node_w2   = (const float*)d_in[16];
    const float* node_b2   = (const float*)d_in[17];
    const float* coord_w1  = (const float*)d_in[18];
    const float* coord_b1  = (const float*)d_in[19];
    const float* coord_w2  = (const float*)d_in[20];
    float* out = (float*)d_out;

    // workspace layout (float elements); total ~9.31M elems = 37.3 MB
    float* ws = (float*)d_ws;
    float* h      = ws;                 // 1,600,000
    float* x4     = ws + 1600000;       //   200,000
    float* Hr     = ws + 1800000;       // 1,600,000
    float* Hc     = ws + 3400000;       // 1,600,000
    float* sea    = ws + 5000000;       //   800,000
    float* aggM   = ws + 5800000;       // 1,600,000
    float* aggX4  = ws + 7400000;       //   200,000 (contiguous after aggM)
    int* rowstart = (int*)(ws + 7600000);   // NN+1
    int* cursor   = (int*)(ws + 7650004);   // NN
    int* srow     = (int*)(ws + 7700004);   // NE
    int* scol     = (int*)(ws + 8500004);   // NE
    int* bsum     = (int*)(ws + 9300004);   // 64
    int* boff     = (int*)(ws + 9300068);   // 64

    hipMemsetAsync(cursor, 0, NN * sizeof(int), stream);
    embed_kernel<<<(NN + 255) / 256, 256, 0, stream>>>(
        data, pos, tptr, emb_in_w, emb_in_b, edge_w1 /*layer 0*/, h, x4, Hr, Hc);
    hist_kernel<<<NE / 256, 256, 0, stream>>>(row, cursor);
    scanA_kernel<<<NB_SCAN, 1024, 0, stream>>>(cursor, rowstart, bsum);
    scanB_kernel<<<1, 64, 0, stream>>>(bsum, boff, rowstart);
    scanC_kernel<<<NB_SCAN, 1024, 0, stream>>>(rowstart, boff);
    hipMemsetAsync(cursor, 0, NN * sizeof(int), stream);
    scatter_kernel<<<NE / 256, 256, 0, stream>>>(row, col, edge_attr, rowstart, cursor, srow, scol, sea);

    for (int l = 0; l < NL; l++) {
        hipMemsetAsync(aggM, 0, (size_t)(NN * HD + NN * 4) * sizeof(float), stream);
        edge_fused_kernel<<<NE / 256, 256, 0, stream>>>(
            x4, srow, scol, sea, Hr, Hc,
            edge_w1 + l * (2*HD+2) * HD, edge_b1 + l * HD,
            edge_w2 + l * HD * HD,       edge_b2 + l * HD,
            coord_w1 + l * HD * HD,      coord_b1 + l * HD,
            coord_w2 + l * HD,
            rowstart, aggM, aggX4);
        const float* eW1n = (l + 1 < NL) ? (edge_w1 + (l + 1) * (2*HD+2) * HD) : nullptr;
        node_fused_kernel<<<NN / 8, 256, 0, stream>>>(
            h, x4, aggM, aggX4, rowstart,
            node_w1 + l * 2 * HD * HD, node_b1 + l * HD,
            node_w2 + l * HD * HD,     node_b2 + l * HD,
            eW1n, Hr, Hc);
    }
    out_kernel<<<(NN + 255) / 256, 256, 0, stream>>>(h, emb_out_w, emb_out_b, out);
}

// Round 5
// 563.870 us; speedup vs baseline: 11.2132x; 1.0575x over previous
//
#include <hip/hip_runtime.h>
#include <hip/hip_fp16.h>

#define NN 50000
#define NE 800000
#define CIN 64
#define COUT 64
#define HD 32
#define NL 4
#define NB_SCAN 49   // ceil(NN/1024)

typedef float f2 __attribute__((ext_vector_type(2)));

__device__ __forceinline__ float silu_f(float v) {
    return v * __builtin_amdgcn_rcpf(1.0f + __expf(-v));
}
__device__ __forceinline__ f2 silu2(f2 v) {
    f2 r; r.x = silu_f(v.x); r.y = silu_f(v.y); return r;
}

// -------- embed: h = [t,data]@W+b ; x4=[pos,0,0]; Hr/Hc layer0; zero cursor/aggM/aggX4
__global__ __launch_bounds__(256) void embed_kernel(
    const float* __restrict__ data, const float* __restrict__ pos,
    const float* __restrict__ tptr,
    const float* __restrict__ W, const float* __restrict__ b,
    const float* __restrict__ eW1_0,
    float* __restrict__ h, float* __restrict__ x4,
    float* __restrict__ Hr, float* __restrict__ Hc,
    int* __restrict__ cursor, float* __restrict__ aggM, float* __restrict__ aggX4)
{
    int n = blockIdx.x * 256 + threadIdx.x;
    if (n >= NN) return;
    float t = tptr[0];
    float d[CIN];
    const float4* dp = (const float4*)(data + (size_t)n * CIN);
#pragma unroll
    for (int i = 0; i < CIN / 4; i++) {
        float4 v = dp[i];
        d[4*i+0] = v.x; d[4*i+1] = v.y; d[4*i+2] = v.z; d[4*i+3] = v.w;
    }
    float acc[HD];
#pragma unroll
    for (int j = 0; j < HD; j++) acc[j] = fmaf(t, W[j], b[j]);   // row 0 = t channel
#pragma unroll
    for (int i = 0; i < CIN; i++) {
        float a = d[i];
#pragma unroll
        for (int j = 0; j < HD; j++) acc[j] = fmaf(a, W[(i + 1) * HD + j], acc[j]);
    }
    float4* hp = (float4*)(h + (size_t)n * HD);
#pragma unroll
    for (int j = 0; j < HD / 4; j++)
        hp[j] = make_float4(acc[4*j], acc[4*j+1], acc[4*j+2], acc[4*j+3]);
    ((float4*)x4)[n] = make_float4(pos[n*2+0], pos[n*2+1], 0.0f, 0.0f);

    // Hr = h @ eW1_0[0:32], Hc = h @ eW1_0[32:64]
    float a1[HD], a2[HD];
#pragma unroll
    for (int j = 0; j < HD; j++) { a1[j] = 0.0f; a2[j] = 0.0f; }
#pragma unroll
    for (int i = 0; i < HD; i++) {
        float z = acc[i];
#pragma unroll
        for (int j = 0; j < HD; j++) {
            a1[j] = fmaf(z, eW1_0[i * HD + j], a1[j]);
            a2[j] = fmaf(z, eW1_0[(HD + i) * HD + j], a2[j]);
        }
    }
    float4* rp = (float4*)(Hr + (size_t)n * HD);
    float4* cp = (float4*)(Hc + (size_t)n * HD);
#pragma unroll
    for (int j = 0; j < HD/4; j++) {
        rp[j] = make_float4(a1[4*j], a1[4*j+1], a1[4*j+2], a1[4*j+3]);
        cp[j] = make_float4(a2[4*j], a2[4*j+1], a2[4*j+2], a2[4*j+3]);
    }

    // zero scratch used with atomics / read-before-write
    cursor[n] = 0;
    float4 z4 = make_float4(0.f, 0.f, 0.f, 0.f);
    float4* za = (float4*)(aggM + (size_t)n * HD);
#pragma unroll
    for (int j = 0; j < HD/4; j++) za[j] = z4;
    ((float4*)aggX4)[n] = z4;
}

// ---------------- sort prologue ----------------
__global__ __launch_bounds__(256) void hist_kernel(const int* __restrict__ row,
                                                   int* __restrict__ cnt)
{
    int e = blockIdx.x * 256 + threadIdx.x;
    if (e < NE) atomicAdd(&cnt[row[e]], 1);
}

__global__ __launch_bounds__(1024) void scanA_kernel(const int* __restrict__ cnt,
                                                     int* __restrict__ rowstart,
                                                     int* __restrict__ bsum)
{
    __shared__ int sd[1024];
    int i = blockIdx.x * 1024 + threadIdx.x;
    int v = (i < NN) ? cnt[i] : 0;
    sd[threadIdx.x] = v;
    __syncthreads();
    for (int off = 1; off < 1024; off <<= 1) {
        int t = (threadIdx.x >= (unsigned)off) ? sd[threadIdx.x - off] : 0;
        __syncthreads();
        sd[threadIdx.x] += t;
        __syncthreads();
    }
    if (i < NN) rowstart[i] = sd[threadIdx.x] - v;   // exclusive within block
    if (threadIdx.x == 1023) bsum[blockIdx.x] = sd[1023];
}

__global__ __launch_bounds__(64) void scanB_kernel(const int* __restrict__ bsum,
                                                   int* __restrict__ boff,
                                                   int* __restrict__ rowstart)
{
    int lane = threadIdx.x;
    int v = (lane < NB_SCAN) ? bsum[lane] : 0;
    int x = v;
    for (int off = 1; off < 64; off <<= 1) {
        int y = __shfl_up(x, off);
        if (lane >= off) x += y;
    }
    if (lane < NB_SCAN) boff[lane] = x - v;          // exclusive
    if (lane == 63) rowstart[NN] = x;                // grand total (= NE)
}

__global__ __launch_bounds__(1024) void scanC_kernel(int* __restrict__ rowstart,
                                                     const int* __restrict__ boff,
                                                     int* __restrict__ cursor)
{
    int i = blockIdx.x * 1024 + threadIdx.x;
    if (i < NN) {
        rowstart[i] += boff[blockIdx.x];
        cursor[i] = 0;                               // re-zero for scatter
    }
}

__global__ __launch_bounds__(256) void scatter_kernel(
    const int* __restrict__ row, const int* __restrict__ col,
    const float* __restrict__ edge_attr,
    const int* __restrict__ rowstart, int* __restrict__ cursor,
    int* __restrict__ srow, int* __restrict__ scol, float* __restrict__ sea)
{
    int e = blockIdx.x * 256 + threadIdx.x;
    if (e >= NE) return;
    int r = row[e];
    int p = rowstart[r] + atomicAdd(&cursor[r], 1);
    srow[p] = r;
    scol[p] = col[e];
    sea[p]  = edge_attr[e];
}

// ------- fused edge kernel: MLPs (f2-packed) + half-LDS block-segmented aggregation ---
__global__ __launch_bounds__(256) void edge_fused_kernel(
    const float* __restrict__ x4,
    const int* __restrict__ srow, const int* __restrict__ scol,
    const float* __restrict__ sea,
    const float* __restrict__ Hr, const float* __restrict__ Hc,
    const float* __restrict__ eW1, const float* __restrict__ eb1,
    const float* __restrict__ eW2, const float* __restrict__ eb2,
    const float* __restrict__ cW1, const float* __restrict__ cb1,
    const float* __restrict__ cW2,
    const int* __restrict__ rowstart,
    float* __restrict__ aggM, float* __restrict__ aggX4)
{
    __shared__ __half sm[256][36];   // [0..31]=m, [32..34]=d*phi, [35] pad; 72B row stride
    __shared__ int snf, snl;
    int tid = threadIdx.x;
    int s_base = blockIdx.x * 256;
    int s = s_base + tid;               // NE % 256 == 0
    int r = srow[s], c = scol[s];
    if (tid == 0)   snf = r;
    if (tid == 255) snl = r;

    float4 xr = ((const float4*)x4)[r];
    float4 xc = ((const float4*)x4)[c];
    float d0 = xr.x - xc.x, d1 = xr.y - xc.y, d2 = xr.z - xc.z;
    float radial = d0*d0 + d1*d1 + d2*d2;
    float ea = sea[s];

    // GEMM1 epilogue: t1 = Hr[r] + Hc[c] + radial*W1[64,:] + ea*W1[65,:] + b1
    const f2* hr2 = (const f2*)(Hr + (size_t)r * HD);
    const f2* hc2 = (const f2*)(Hc + (size_t)c * HD);
    const f2* wr2 = (const f2*)(eW1 + 64 * HD);
    const f2* we2 = (const f2*)(eW1 + 65 * HD);
    const f2* be2 = (const f2*)eb1;
    f2 rad2; rad2.x = radial; rad2.y = radial;
    f2 eav;  eav.x  = ea;     eav.y  = ea;
    f2 t1[HD/2];
#pragma unroll
    for (int j = 0; j < HD/2; j++) {
        f2 v = hr2[j] + hc2[j] + be2[j];
        v = v + rad2 * wr2[j];
        v = v + eav  * we2[j];
        t1[j] = silu2(v);
    }

    // GEMM2: 32 -> 32, silu -> m  (f2-packed, weights via uniform s_load)
    f2 m2[HD/2];
#pragma unroll
    for (int j = 0; j < HD/2; j++) m2[j] = ((const f2*)eb2)[j];
#pragma unroll
    for (int i = 0; i < HD; i++) {
        float a = (i & 1) ? t1[i >> 1].y : t1[i >> 1].x;
        f2 av; av.x = a; av.y = a;
        const f2* w2 = (const f2*)(eW2 + i * HD);
#pragma unroll
        for (int j = 0; j < HD/2; j++) m2[j] += av * w2[j];
    }
#pragma unroll
    for (int j = 0; j < HD/2; j++) m2[j] = silu2(m2[j]);

    // stage m into LDS early (half2), overlaps with coord MLP
#pragma unroll
    for (int j = 0; j < HD/2; j++)
        *(__half2*)&sm[tid][2*j] = __floats2half2_rn(m2[j].x, m2[j].y);

    // coord MLP: m -> 32 (silu) -> 1
    f2 c2[HD/2];
#pragma unroll
    for (int j = 0; j < HD/2; j++) c2[j] = ((const f2*)cb1)[j];
#pragma unroll
    for (int i = 0; i < HD; i++) {
        float a = (i & 1) ? m2[i >> 1].y : m2[i >> 1].x;
        f2 av; av.x = a; av.y = a;
        const f2* w2 = (const f2*)(cW1 + i * HD);
#pragma unroll
        for (int j = 0; j < HD/2; j++) c2[j] += av * w2[j];
    }
    float phi = 0.0f;
#pragma unroll
    for (int j = 0; j < HD/2; j++) {
        f2 sc = silu2(c2[j]);
        phi = fmaf(sc.x, cW2[2*j], phi);
        phi = fmaf(sc.y, cW2[2*j+1], phi);
    }

    *(__half2*)&sm[tid][32] = __floats2half2_rn(d0 * phi, d1 * phi);
    sm[tid][34] = __float2half(d2 * phi);
    __syncthreads();

    // block-segmented reduction: 8 groups of 32 lanes; group g handles nodes nf+g, nf+g+8, ...
    int g = tid >> 5, ch = tid & 31;
    int nf = snf, nl = snl;
    for (int node = nf + g; node <= nl; node += 8) {
        int lo = rowstart[node], hi = rowstart[node + 1];
        int clo = lo - s_base; if (clo < 0) clo = 0;
        int chi = hi - s_base; if (chi > 256) chi = 256;
        if (chi <= clo) continue;                       // zero-degree node in range
        float am = 0.0f;
        for (int j = clo; j < chi; j++) am += __half2float(sm[j][ch]);
        bool interior = (lo >= s_base) && (hi <= s_base + 256);
        if (interior) aggM[(size_t)node * HD + ch] = am;
        else          atomicAdd(&aggM[(size_t)node * HD + ch], am);
        if (ch < 3) {
            float ax = 0.0f;
            for (int j = clo; j < chi; j++) ax += __half2float(sm[j][32 + ch]);
            if (interior) aggX4[(size_t)node * 4 + ch] = ax;
            else          atomicAdd(&aggX4[(size_t)node * 4 + ch], ax);
        }
    }
}

// ------- node update (+ Hr/Hc for next layer, or fused output projection on last) -----
__global__ __launch_bounds__(256) void node_fused_kernel(
    float* __restrict__ h, float* __restrict__ x4,
    float* __restrict__ aggM, float* __restrict__ aggX4,
    const int* __restrict__ rowstart,
    const float* __restrict__ nW1, const float* __restrict__ nb1,
    const float* __restrict__ nW2, const float* __restrict__ nb2,
    const float* __restrict__ eW1n,   // next layer edge_w1 (null on last layer)
    float* __restrict__ Hr, float* __restrict__ Hc,
    const float* __restrict__ Wout, const float* __restrict__ bout,
    float* __restrict__ out)          // non-null on last layer
{
    __shared__ float sIn[8][2*HD];
    __shared__ float sU[8][HD];
    __shared__ float sH[8][HD];
    int local = threadIdx.x >> 5;
    int ch    = threadIdx.x & 31;
    int n = blockIdx.x * 8 + local;          // NN == 6250*8, exact
    float hv = h[(size_t)n * HD + ch];
    float am = aggM[(size_t)n * HD + ch];
    aggM[(size_t)n * HD + ch] = 0.0f;        // re-zero for next layer's boundary atomics
    sIn[local][ch]      = hv;
    sIn[local][HD + ch] = am;
    if (ch < 3) {
        int cnt = rowstart[n + 1] - rowstart[n];
        float cf = (cnt < 1) ? 1.0f : (float)cnt;
        x4[(size_t)n * 4 + ch] += aggX4[(size_t)n * 4 + ch] / cf;
        aggX4[(size_t)n * 4 + ch] = 0.0f;
    }
    __syncthreads();
    float u1 = nb1[ch];
#pragma unroll 8
    for (int i = 0; i < 2*HD; i++) u1 = fmaf(sIn[local][i], nW1[i * HD + ch], u1);
    u1 = silu_f(u1);
    sU[local][ch] = u1;
    __syncthreads();
    float u2 = nb2[ch];
#pragma unroll 8
    for (int i = 0; i < HD; i++) u2 = fmaf(sU[local][i], nW2[i * HD + ch], u2);
    float hn = hv + u2;

    if (eW1n != nullptr) {
        h[(size_t)n * HD + ch] = hn;
        sH[local][ch] = hn;
        __syncthreads();
        float a = 0.0f, b = 0.0f;
#pragma unroll 8
        for (int i = 0; i < HD; i++) {
            float z = sH[local][i];
            a = fmaf(z, eW1n[i * HD + ch], a);
            b = fmaf(z, eW1n[(HD + i) * HD + ch], b);
        }
        Hr[(size_t)n * HD + ch] = a;
        Hc[(size_t)n * HD + ch] = b;
    } else {
        // fused output projection: out[n,:] = hn @ Wout + bout
        sH[local][ch] = hn;
        __syncthreads();
        float o0 = bout[ch], o1 = bout[HD + ch];
#pragma unroll 8
        for (int i = 0; i < HD; i++) {
            float z = sH[local][i];
            o0 = fmaf(z, Wout[i * COUT + ch], o0);
            o1 = fmaf(z, Wout[i * COUT + HD + ch], o1);
        }
        out[(size_t)n * COUT + ch]      = o0;
        out[(size_t)n * COUT + HD + ch] = o1;
    }
}

extern "C" void kernel_launch(void* const* d_in, const int* in_sizes, int n_in,
                              void* d_out, int out_size, void* d_ws, size_t ws_size,
                              hipStream_t stream) {
    // setup_inputs() dict insertion order:
    //  0 data, 1 pos, 2 edge_attr, 3 t, 4 row, 5 col,
    //  6 emb_in_w, 7 emb_in_b, 8 emb_out_w, 9 emb_out_b,
    // 10 edge_w1, 11 edge_b1, 12 edge_w2, 13 edge_b2,
    // 14 node_w1, 15 node_b1, 16 node_w2, 17 node_b2,
    // 18 coord_w1, 19 coord_b1, 20 coord_w2
    const float* data      = (const float*)d_in[0];
    const float* pos       = (const float*)d_in[1];
    const float* edge_attr = (const float*)d_in[2];
    const float* tptr      = (const float*)d_in[3];
    const int*   row       = (const int*)d_in[4];
    const int*   col       = (const int*)d_in[5];
    const float* emb_in_w  = (const float*)d_in[6];
    const float* emb_in_b  = (const float*)d_in[7];
    const float* emb_out_w = (const float*)d_in[8];
    const float* emb_out_b = (const float*)d_in[9];
    const float* edge_w1   = (const float*)d_in[10];
    const float* edge_b1   = (const float*)d_in[11];
    const float* edge_w2   = (const float*)d_in[12];
    const float* edge_b2   = (const float*)d_in[13];
    const float* node_w1   = (const float*)d_in[14];
    const float* node_b1   = (const float*)d_in[15];
    const float* node_w2   = (const float*)d_in[16];
    const float* node_b2   = (const float*)d_in[17];
    const float* coord_w1  = (const float*)d_in[18];
    const float* coord_b1  = (const float*)d_in[19];
    const float* coord_w2  = (const float*)d_in[20];
    float* out = (float*)d_out;

    // workspace layout (float elements); ~9.3M elems = 37.3 MB
    float* ws = (float*)d_ws;
    float* h      = ws;                 // 1,600,000
    float* x4     = ws + 1600000;       //   200,000
    float* Hr     = ws + 1800000;       // 1,600,000
    float* Hc     = ws + 3400000;       // 1,600,000
    float* sea    = ws + 5000000;       //   800,000
    float* aggM   = ws + 5800000;       // 1,600,000
    float* aggX4  = ws + 7400000;       //   200,000
    int* rowstart = (int*)(ws + 7600000);   // NN+1
    int* cursor   = (int*)(ws + 7650004);   // NN
    int* srow     = (int*)(ws + 7700004);   // NE
    int* scol     = (int*)(ws + 8500004);   // NE
    int* bsum     = (int*)(ws + 9300004);   // 64
    int* boff     = (int*)(ws + 9300068);   // 64

    embed_kernel<<<(NN + 255) / 256, 256, 0, stream>>>(
        data, pos, tptr, emb_in_w, emb_in_b, edge_w1 /*layer 0*/,
        h, x4, Hr, Hc, cursor, aggM, aggX4);
    hist_kernel<<<NE / 256, 256, 0, stream>>>(row, cursor);
    scanA_kernel<<<NB_SCAN, 1024, 0, stream>>>(cursor, rowstart, bsum);
    scanB_kernel<<<1, 64, 0, stream>>>(bsum, boff, rowstart);
    scanC_kernel<<<NB_SCAN, 1024, 0, stream>>>(rowstart, boff, cursor);
    scatter_kernel<<<NE / 256, 256, 0, stream>>>(row, col, edge_attr, rowstart, cursor, srow, scol, sea);

    for (int l = 0; l < NL; l++) {
        edge_fused_kernel<<<NE / 256, 256, 0, stream>>>(
            x4, srow, scol, sea, Hr, Hc,
            edge_w1 + l * (2*HD+2) * HD, edge_b1 + l * HD,
            edge_w2 + l * HD * HD,       edge_b2 + l * HD,
            coord_w1 + l * HD * HD,      coord_b1 + l * HD,
            coord_w2 + l * HD,
            rowstart, aggM, aggX4);
        bool lastl = (l + 1 == NL);
        node_fused_kernel<<<NN / 8, 256, 0, stream>>>(
            h, x4, aggM, aggX4, rowstart,
            node_w1 + l * 2 * HD * HD, node_b1 + l * HD,
            node_w2 + l * HD * HD,     node_b2 + l * HD,
            lastl ? nullptr : (edge_w1 + (l + 1) * (2*HD+2) * HD), Hr, Hc,
            emb_out_w, emb_out_b, lastl ? out : nullptr);
    }
}

// Round 6
// 470.900 us; speedup vs baseline: 13.4270x; 1.1974x over previous
//
#include <hip/hip_runtime.h>
#include <hip/hip_fp16.h>

#define NN 50000
#define NE 800000
#define CIN 64
#define COUT 64
#define HD 32
#define NL 4
#define NB_SCAN 49   // ceil(NN/1024)

typedef float f32x4 __attribute__((ext_vector_type(4)));
typedef _Float16 half8 __attribute__((ext_vector_type(8)));

__device__ __forceinline__ float silu_f(float v) {
    return v * __builtin_amdgcn_rcpf(1.0f + __expf(-v));
}

// -------- embed: h = [t,data]@W+b ; x4=[pos,0,0]; Hr/Hc layer0; zero cursor/aggM/aggX4
__global__ __launch_bounds__(256) void embed_kernel(
    const float* __restrict__ data, const float* __restrict__ pos,
    const float* __restrict__ tptr,
    const float* __restrict__ W, const float* __restrict__ b,
    const float* __restrict__ eW1_0,
    float* __restrict__ h, float* __restrict__ x4,
    float* __restrict__ Hr, float* __restrict__ Hc,
    int* __restrict__ cursor, float* __restrict__ aggM, float* __restrict__ aggX4)
{
    int n = blockIdx.x * 256 + threadIdx.x;
    if (n >= NN) return;
    float t = tptr[0];
    float d[CIN];
    const float4* dp = (const float4*)(data + (size_t)n * CIN);
#pragma unroll
    for (int i = 0; i < CIN / 4; i++) {
        float4 v = dp[i];
        d[4*i+0] = v.x; d[4*i+1] = v.y; d[4*i+2] = v.z; d[4*i+3] = v.w;
    }
    float acc[HD];
#pragma unroll
    for (int j = 0; j < HD; j++) acc[j] = fmaf(t, W[j], b[j]);   // row 0 = t channel
#pragma unroll
    for (int i = 0; i < CIN; i++) {
        float a = d[i];
#pragma unroll
        for (int j = 0; j < HD; j++) acc[j] = fmaf(a, W[(i + 1) * HD + j], acc[j]);
    }
    float4* hp = (float4*)(h + (size_t)n * HD);
#pragma unroll
    for (int j = 0; j < HD / 4; j++)
        hp[j] = make_float4(acc[4*j], acc[4*j+1], acc[4*j+2], acc[4*j+3]);
    ((float4*)x4)[n] = make_float4(pos[n*2+0], pos[n*2+1], 0.0f, 0.0f);

    float a1[HD], a2[HD];
#pragma unroll
    for (int j = 0; j < HD; j++) { a1[j] = 0.0f; a2[j] = 0.0f; }
#pragma unroll
    for (int i = 0; i < HD; i++) {
        float z = acc[i];
#pragma unroll
        for (int j = 0; j < HD; j++) {
            a1[j] = fmaf(z, eW1_0[i * HD + j], a1[j]);
            a2[j] = fmaf(z, eW1_0[(HD + i) * HD + j], a2[j]);
        }
    }
    float4* rp = (float4*)(Hr + (size_t)n * HD);
    float4* cp = (float4*)(Hc + (size_t)n * HD);
#pragma unroll
    for (int j = 0; j < HD/4; j++) {
        rp[j] = make_float4(a1[4*j], a1[4*j+1], a1[4*j+2], a1[4*j+3]);
        cp[j] = make_float4(a2[4*j], a2[4*j+1], a2[4*j+2], a2[4*j+3]);
    }

    cursor[n] = 0;
    float4 z4 = make_float4(0.f, 0.f, 0.f, 0.f);
    float4* za = (float4*)(aggM + (size_t)n * HD);
#pragma unroll
    for (int j = 0; j < HD/4; j++) za[j] = z4;
    ((float4*)aggX4)[n] = z4;
}

// -------- prep: pack W2 / cW1 into MFMA B-fragment order (f16), all layers --------
// B[k][j] frag: lane l supplies col j = 16*nt + (l&15), k = 8*(l>>4) + e, e=0..7
__global__ __launch_bounds__(128) void prep_kernel(
    const float* __restrict__ eW2, const float* __restrict__ cW1,
    __half* __restrict__ w2B, __half* __restrict__ cW1B)
{
    int l  = blockIdx.x;
    int nt = threadIdx.x >> 6;
    int wl = threadIdx.x & 63;
    int rsel = wl & 15, ksel = wl >> 4;
#pragma unroll
    for (int e = 0; e < 8; e++) {
        int k = 8 * ksel + e;
        int j = 16 * nt + rsel;
        size_t o = ((size_t)(l * 2 + nt) * 64 + wl) * 8 + e;
        w2B[o]  = __float2half(eW2[(size_t)l * HD * HD + k * HD + j]);
        cW1B[o] = __float2half(cW1[(size_t)l * HD * HD + k * HD + j]);
    }
}

// ---------------- sort prologue ----------------
__global__ __launch_bounds__(256) void hist_kernel(const int* __restrict__ row,
                                                   int* __restrict__ cnt)
{
    int e = blockIdx.x * 256 + threadIdx.x;
    if (e < NE) atomicAdd(&cnt[row[e]], 1);
}

__global__ __launch_bounds__(1024) void scanA_kernel(const int* __restrict__ cnt,
                                                     int* __restrict__ rowstart,
                                                     int* __restrict__ bsum)
{
    __shared__ int sd[1024];
    int i = blockIdx.x * 1024 + threadIdx.x;
    int v = (i < NN) ? cnt[i] : 0;
    sd[threadIdx.x] = v;
    __syncthreads();
    for (int off = 1; off < 1024; off <<= 1) {
        int t = (threadIdx.x >= (unsigned)off) ? sd[threadIdx.x - off] : 0;
        __syncthreads();
        sd[threadIdx.x] += t;
        __syncthreads();
    }
    if (i < NN) rowstart[i] = sd[threadIdx.x] - v;   // exclusive within block
    if (threadIdx.x == 1023) bsum[blockIdx.x] = sd[1023];
}

// scanC with inline block-sum scan (scanB folded in)
__global__ __launch_bounds__(1024) void scanC_kernel(int* __restrict__ rowstart,
                                                     const int* __restrict__ bsum,
                                                     int* __restrict__ cursor)
{
    __shared__ int sb[64];
    if (threadIdx.x < 64) {
        int lane = threadIdx.x;
        int v = (lane < NB_SCAN) ? bsum[lane] : 0;
        int x = v;
        for (int off = 1; off < 64; off <<= 1) {
            int y = __shfl_up(x, off);
            if (lane >= off) x += y;
        }
        sb[lane] = x - v;                            // exclusive
        if (lane == 63) rowstart[NN] = x;            // grand total (= NE), same in all blocks
    }
    __syncthreads();
    int i = blockIdx.x * 1024 + threadIdx.x;
    if (i < NN) {
        rowstart[i] += sb[blockIdx.x];
        cursor[i] = 0;                               // re-zero for scatter
    }
}

__global__ __launch_bounds__(256) void scatter_kernel(
    const int* __restrict__ row, const int* __restrict__ col,
    const float* __restrict__ edge_attr,
    const int* __restrict__ rowstart, int* __restrict__ cursor,
    int* __restrict__ srow, int* __restrict__ scol, float* __restrict__ sea)
{
    int e = blockIdx.x * 256 + threadIdx.x;
    if (e >= NE) return;
    int r = row[e];
    int p = rowstart[r] + atomicAdd(&cursor[r], 1);
    srow[p] = r;
    scol[p] = col[e];
    sea[p]  = edge_attr[e];
}

// ------- fused edge kernel: epilogue(VALU) + GEMM2/coord (MFMA) + segmented agg -------
__global__ __launch_bounds__(256) void edge_fused_kernel(
    const float* __restrict__ x4,
    const int* __restrict__ srow, const int* __restrict__ scol,
    const float* __restrict__ sea,
    const float* __restrict__ Hr, const float* __restrict__ Hc,
    const float* __restrict__ eW1, const float* __restrict__ eb1,
    const float* __restrict__ eb2,
    const __half* __restrict__ w2Bl, const __half* __restrict__ cW1Bl,
    const float* __restrict__ cb1, const float* __restrict__ cW2,
    const int* __restrict__ rowstart,
    float* __restrict__ aggM, float* __restrict__ aggX4)
{
    __shared__ __align__(16) __half At[256][40];   // t1 (f16), then reused for m (f16)
    __shared__ __half sx[256][4];                  // d*phi
    __shared__ float  phib[256];
    __shared__ int snf, snl;
    int tid = threadIdx.x;
    int s_base = blockIdx.x * 256;
    int s = s_base + tid;                          // NE % 256 == 0
    int r = srow[s], c = scol[s];
    if (tid == 0)   snf = r;
    if (tid == 255) snl = r;

    float4 xr = ((const float4*)x4)[r];
    float4 xc = ((const float4*)x4)[c];
    float d0 = xr.x - xc.x, d1 = xr.y - xc.y, d2 = xr.z - xc.z;
    float radial = d0*d0 + d1*d1 + d2*d2;
    float ea = sea[s];

    // ---- P1: t1 = silu(Hr[r] + Hc[c] + radial*W1[64,:] + ea*W1[65,:] + b1) -> LDS f16
    const f32x4* hrp = (const f32x4*)(Hr + (size_t)r * HD);
    const f32x4* hcp = (const f32x4*)(Hc + (size_t)c * HD);
    const f32x4* w64 = (const f32x4*)(eW1 + 64 * HD);
    const f32x4* w65 = (const f32x4*)(eW1 + 65 * HD);
    const f32x4* bb1 = (const f32x4*)eb1;
    int wbuf[16];
#pragma unroll
    for (int i = 0; i < 8; i++) {
        f32x4 v = hrp[i] + hcp[i] + bb1[i] + radial * w64[i] + ea * w65[i];
        v.x = silu_f(v.x); v.y = silu_f(v.y); v.z = silu_f(v.z); v.w = silu_f(v.w);
        __half2 p0 = __floats2half2_rn(v.x, v.y);
        __half2 p1 = __floats2half2_rn(v.z, v.w);
        wbuf[2*i]   = *(int*)&p0;
        wbuf[2*i+1] = *(int*)&p1;
    }
    int4* arow = (int4*)&At[tid][0];
#pragma unroll
    for (int q = 0; q < 4; q++)
        arow[q] = make_int4(wbuf[4*q], wbuf[4*q+1], wbuf[4*q+2], wbuf[4*q+3]);

    int wl = tid & 63;
    int wbase = tid & 192;           // wave's private 64-row LDS window
    int rsel = wl & 15, ksel = wl >> 4;

    // ---- P2: GEMM2 via MFMA: M[64,32] = At[64,32] @ W2 + b2, silu -> m (back to LDS)
    half8 bw0 = ((const half8*)w2Bl)[wl];
    half8 bw1 = ((const half8*)w2Bl)[64 + wl];
    float bc0 = eb2[rsel], bc1 = eb2[16 + rsel];
    f32x4 acc[4][2];
#pragma unroll
    for (int mt = 0; mt < 4; mt++) {
        acc[mt][0] = (f32x4){bc0, bc0, bc0, bc0};
        acc[mt][1] = (f32x4){bc1, bc1, bc1, bc1};
    }
#pragma unroll
    for (int mt = 0; mt < 4; mt++) {
        half8 af = *(const half8*)&At[wbase + 16*mt + rsel][8*ksel];
        acc[mt][0] = __builtin_amdgcn_mfma_f32_16x16x32_f16(af, bw0, acc[mt][0], 0, 0, 0);
        acc[mt][1] = __builtin_amdgcn_mfma_f32_16x16x32_f16(af, bw1, acc[mt][1], 0, 0, 0);
    }
    // silu + write m into the same LDS window (C-layout -> row-major f16)
#pragma unroll
    for (int mt = 0; mt < 4; mt++)
#pragma unroll
        for (int nt = 0; nt < 2; nt++)
#pragma unroll
            for (int q = 0; q < 4; q++) {
                float mv = silu_f(acc[mt][nt][q]);
                At[wbase + 16*mt + 4*ksel + q][16*nt + rsel] = __float2half(mv);
            }

    // ---- P3: coord MLP via MFMA: C1[64,32] = m @ cW1 + cb1
    half8 cw0 = ((const half8*)cW1Bl)[wl];
    half8 cw1 = ((const half8*)cW1Bl)[64 + wl];
    float cc0 = cb1[rsel], cc1 = cb1[16 + rsel];
    f32x4 cacc[4][2];
#pragma unroll
    for (int mt = 0; mt < 4; mt++) {
        cacc[mt][0] = (f32x4){cc0, cc0, cc0, cc0};
        cacc[mt][1] = (f32x4){cc1, cc1, cc1, cc1};
    }
#pragma unroll
    for (int mt = 0; mt < 4; mt++) {
        half8 am = *(const half8*)&At[wbase + 16*mt + rsel][8*ksel];
        cacc[mt][0] = __builtin_amdgcn_mfma_f32_16x16x32_f16(am, cw0, cacc[mt][0], 0, 0, 0);
        cacc[mt][1] = __builtin_amdgcn_mfma_f32_16x16x32_f16(am, cw1, cacc[mt][1], 0, 0, 0);
    }

    // ---- P4: phi[row] = sum_j silu(C1[row][j]) * cW2[j]; reduce across 16-lane cols
    float cw2a = cW2[rsel], cw2b = cW2[16 + rsel];
    float p[4][4];
#pragma unroll
    for (int mt = 0; mt < 4; mt++)
#pragma unroll
        for (int q = 0; q < 4; q++)
            p[mt][q] = silu_f(cacc[mt][0][q]) * cw2a + silu_f(cacc[mt][1][q]) * cw2b;
#pragma unroll
    for (int dd = 1; dd < 16; dd <<= 1)
#pragma unroll
        for (int mt = 0; mt < 4; mt++)
#pragma unroll
            for (int q = 0; q < 4; q++)
                p[mt][q] += __shfl_xor(p[mt][q], dd);
    if (rsel == 0) {
#pragma unroll
        for (int mt = 0; mt < 4; mt++)
#pragma unroll
            for (int q = 0; q < 4; q++)
                phib[wbase + 16*mt + 4*ksel + q] = p[mt][q];
    }
    float phi = phib[tid];

    *(__half2*)&sx[tid][0] = __floats2half2_rn(d0 * phi, d1 * phi);
    sx[tid][2] = __float2half(d2 * phi);
    __syncthreads();

    // ---- P5: block-segmented reduction (m read from At as f16)
    int g = tid >> 5, ch = tid & 31;
    int nf = snf, nl = snl;
    for (int node = nf + g; node <= nl; node += 8) {
        int lo = rowstart[node], hi = rowstart[node + 1];
        int clo = lo - s_base; if (clo < 0) clo = 0;
        int chi = hi - s_base; if (chi > 256) chi = 256;
        if (chi <= clo) continue;                       // zero-degree node in range
        float am = 0.0f;
        for (int j = clo; j < chi; j++) am += __half2float(At[j][ch]);
        bool interior = (lo >= s_base) && (hi <= s_base + 256);
        if (interior) aggM[(size_t)node * HD + ch] = am;
        else          atomicAdd(&aggM[(size_t)node * HD + ch], am);
        if (ch < 3) {
            float ax = 0.0f;
            for (int j = clo; j < chi; j++) ax += __half2float(sx[j][ch]);
            if (interior) aggX4[(size_t)node * 4 + ch] = ax;
            else          atomicAdd(&aggX4[(size_t)node * 4 + ch], ax);
        }
    }
}

// ------- node update (+ Hr/Hc for next layer, or fused output projection on last) -----
__global__ __launch_bounds__(256) void node_fused_kernel(
    float* __restrict__ h, float* __restrict__ x4,
    float* __restrict__ aggM, float* __restrict__ aggX4,
    const int* __restrict__ rowstart,
    const float* __restrict__ nW1, const float* __restrict__ nb1,
    const float* __restrict__ nW2, const float* __restrict__ nb2,
    const float* __restrict__ eW1n,   // next layer edge_w1 (null on last layer)
    float* __restrict__ Hr, float* __restrict__ Hc,
    const float* __restrict__ Wout, const float* __restrict__ bout,
    float* __restrict__ out)          // non-null on last layer
{
    __shared__ float sIn[8][2*HD];
    __shared__ float sU[8][HD];
    __shared__ float sH[8][HD];
    int local = threadIdx.x >> 5;
    int ch    = threadIdx.x & 31;
    int n = blockIdx.x * 8 + local;          // NN == 6250*8, exact
    float hv = h[(size_t)n * HD + ch];
    float am = aggM[(size_t)n * HD + ch];
    aggM[(size_t)n * HD + ch] = 0.0f;        // re-zero for next layer's boundary atomics
    sIn[local][ch]      = hv;
    sIn[local][HD + ch] = am;
    if (ch < 3) {
        int cnt = rowstart[n + 1] - rowstart[n];
        float cf = (cnt < 1) ? 1.0f : (float)cnt;
        x4[(size_t)n * 4 + ch] += aggX4[(size_t)n * 4 + ch] / cf;
        aggX4[(size_t)n * 4 + ch] = 0.0f;
    }
    __syncthreads();
    float u1 = nb1[ch];
#pragma unroll 8
    for (int i = 0; i < 2*HD; i++) u1 = fmaf(sIn[local][i], nW1[i * HD + ch], u1);
    u1 = silu_f(u1);
    sU[local][ch] = u1;
    __syncthreads();
    float u2 = nb2[ch];
#pragma unroll 8
    for (int i = 0; i < HD; i++) u2 = fmaf(sU[local][i], nW2[i * HD + ch], u2);
    float hn = hv + u2;

    if (eW1n != nullptr) {
        h[(size_t)n * HD + ch] = hn;
        sH[local][ch] = hn;
        __syncthreads();
        float a = 0.0f, b = 0.0f;
#pragma unroll 8
        for (int i = 0; i < HD; i++) {
            float z = sH[local][i];
            a = fmaf(z, eW1n[i * HD + ch], a);
            b = fmaf(z, eW1n[(HD + i) * HD + ch], b);
        }
        Hr[(size_t)n * HD + ch] = a;
        Hc[(size_t)n * HD + ch] = b;
    } else {
        sH[local][ch] = hn;
        __syncthreads();
        float o0 = bout[ch], o1 = bout[HD + ch];
#pragma unroll 8
        for (int i = 0; i < HD; i++) {
            float z = sH[local][i];
            o0 = fmaf(z, Wout[i * COUT + ch], o0);
            o1 = fmaf(z, Wout[i * COUT + HD + ch], o1);
        }
        out[(size_t)n * COUT + ch]      = o0;
        out[(size_t)n * COUT + HD + ch] = o1;
    }
}

extern "C" void kernel_launch(void* const* d_in, const int* in_sizes, int n_in,
                              void* d_out, int out_size, void* d_ws, size_t ws_size,
                              hipStream_t stream) {
    // setup_inputs() dict insertion order:
    //  0 data, 1 pos, 2 edge_attr, 3 t, 4 row, 5 col,
    //  6 emb_in_w, 7 emb_in_b, 8 emb_out_w, 9 emb_out_b,
    // 10 edge_w1, 11 edge_b1, 12 edge_w2, 13 edge_b2,
    // 14 node_w1, 15 node_b1, 16 node_w2, 17 node_b2,
    // 18 coord_w1, 19 coord_b1, 20 coord_w2
    const float* data      = (const float*)d_in[0];
    const float* pos       = (const float*)d_in[1];
    const float* edge_attr = (const float*)d_in[2];
    const float* tptr      = (const float*)d_in[3];
    const int*   row       = (const int*)d_in[4];
    const int*   col       = (const int*)d_in[5];
    const float* emb_in_w  = (const float*)d_in[6];
    const float* emb_in_b  = (const float*)d_in[7];
    const float* emb_out_w = (const float*)d_in[8];
    const float* emb_out_b = (const float*)d_in[9];
    const float* edge_w1   = (const float*)d_in[10];
    const float* edge_b1   = (const float*)d_in[11];
    const float* edge_w2   = (const float*)d_in[12];
    const float* edge_b2   = (const float*)d_in[13];
    const float* node_w1   = (const float*)d_in[14];
    const float* node_b1   = (const float*)d_in[15];
    const float* node_w2   = (const float*)d_in[16];
    const float* node_b2   = (const float*)d_in[17];
    const float* coord_w1  = (const float*)d_in[18];
    const float* coord_b1  = (const float*)d_in[19];
    const float* coord_w2  = (const float*)d_in[20];
    float* out = (float*)d_out;

    // workspace layout (float elements); ~9.32M elems = 37.3 MB
    float* ws = (float*)d_ws;
    float* h      = ws;                 // 1,600,000
    float* x4     = ws + 1600000;       //   200,000
    float* Hr     = ws + 1800000;       // 1,600,000
    float* Hc     = ws + 3400000;       // 1,600,000
    float* sea    = ws + 5000000;       //   800,000
    float* aggM   = ws + 5800000;       // 1,600,000
    float* aggX4  = ws + 7400000;       //   200,000
    int* rowstart = (int*)(ws + 7600000);   // NN+1
    int* cursor   = (int*)(ws + 7650004);   // NN
    int* srow     = (int*)(ws + 7700004);   // NE
    int* scol     = (int*)(ws + 8500004);   // NE
    int* bsum     = (int*)(ws + 9300004);   // 64
    __half* w2B   = (__half*)(ws + 9310000);   // NL*2*64*8 halfs (16B-aligned)
    __half* cW1B  = w2B + (size_t)NL * 1024;   // NL*2*64*8 halfs

    embed_kernel<<<(NN + 255) / 256, 256, 0, stream>>>(
        data, pos, tptr, emb_in_w, emb_in_b, edge_w1 /*layer 0*/,
        h, x4, Hr, Hc, cursor, aggM, aggX4);
    prep_kernel<<<NL, 128, 0, stream>>>(edge_w2, coord_w1, w2B, cW1B);
    hist_kernel<<<NE / 256, 256, 0, stream>>>(row, cursor);
    scanA_kernel<<<NB_SCAN, 1024, 0, stream>>>(cursor, rowstart, bsum);
    scanC_kernel<<<NB_SCAN, 1024, 0, stream>>>(rowstart, bsum, cursor);
    scatter_kernel<<<NE / 256, 256, 0, stream>>>(row, col, edge_attr, rowstart, cursor, srow, scol, sea);

    for (int l = 0; l < NL; l++) {
        edge_fused_kernel<<<NE / 256, 256, 0, stream>>>(
            x4, srow, scol, sea, Hr, Hc,
            edge_w1 + l * (2*HD+2) * HD, edge_b1 + l * HD,
            edge_b2 + l * HD,
            w2B + (size_t)l * 1024, cW1B + (size_t)l * 1024,
            coord_b1 + l * HD, coord_w2 + l * HD,
            rowstart, aggM, aggX4);
        bool lastl = (l + 1 == NL);
        node_fused_kernel<<<NN / 8, 256, 0, stream>>>(
            h, x4, aggM, aggX4, rowstart,
            node_w1 + l * 2 * HD * HD, node_b1 + l * HD,
            node_w2 + l * HD * HD,     node_b2 + l * HD,
            lastl ? nullptr : (edge_w1 + (l + 1) * (2*HD+2) * HD), Hr, Hc,
            emb_out_w, emb_out_b, lastl ? out : nullptr);
    }
}

// Round 8
// 458.919 us; speedup vs baseline: 13.7776x; 1.0261x over previous
//
#include <hip/hip_runtime.h>
#include <hip/hip_fp16.h>

#define NN 50000
#define NE 800000
#define CIN 64
#define COUT 64
#define HD 32
#define NL 4
#define NB_SCAN 49   // ceil(NN/1024)

typedef float f32x4 __attribute__((ext_vector_type(4)));
typedef _Float16 half8 __attribute__((ext_vector_type(8)));

__device__ __forceinline__ float silu_f(float v) {
    return v * __builtin_amdgcn_rcpf(1.0f + __expf(-v));
}

// -------- embed: h = [t,data]@W+b ; x4=[pos,0,0]; Hr/Hc (f16) layer0; zero scratch ----
__global__ __launch_bounds__(256) void embed_kernel(
    const float* __restrict__ data, const float* __restrict__ pos,
    const float* __restrict__ tptr,
    const float* __restrict__ W, const float* __restrict__ b,
    const float* __restrict__ eW1_0,
    float* __restrict__ h, float* __restrict__ x4,
    __half* __restrict__ Hrh, __half* __restrict__ Hch,
    int* __restrict__ cursor, float* __restrict__ aggM, float* __restrict__ aggX4)
{
    int n = blockIdx.x * 256 + threadIdx.x;
    if (n >= NN) return;
    float t = tptr[0];
    float d[CIN];
    const float4* dp = (const float4*)(data + (size_t)n * CIN);
#pragma unroll
    for (int i = 0; i < CIN / 4; i++) {
        float4 v = dp[i];
        d[4*i+0] = v.x; d[4*i+1] = v.y; d[4*i+2] = v.z; d[4*i+3] = v.w;
    }
    float acc[HD];
#pragma unroll
    for (int j = 0; j < HD; j++) acc[j] = fmaf(t, W[j], b[j]);   // row 0 = t channel
#pragma unroll
    for (int i = 0; i < CIN; i++) {
        float a = d[i];
#pragma unroll
        for (int j = 0; j < HD; j++) acc[j] = fmaf(a, W[(i + 1) * HD + j], acc[j]);
    }
    float4* hp = (float4*)(h + (size_t)n * HD);
#pragma unroll
    for (int j = 0; j < HD / 4; j++)
        hp[j] = make_float4(acc[4*j], acc[4*j+1], acc[4*j+2], acc[4*j+3]);
    ((float4*)x4)[n] = make_float4(pos[n*2+0], pos[n*2+1], 0.0f, 0.0f);

    float a1[HD], a2[HD];
#pragma unroll
    for (int j = 0; j < HD; j++) { a1[j] = 0.0f; a2[j] = 0.0f; }
#pragma unroll
    for (int i = 0; i < HD; i++) {
        float z = acc[i];
#pragma unroll
        for (int j = 0; j < HD; j++) {
            a1[j] = fmaf(z, eW1_0[i * HD + j], a1[j]);
            a2[j] = fmaf(z, eW1_0[(HD + i) * HD + j], a2[j]);
        }
    }
    // pack ALL 32 channels to f16: 16 half2 words -> 4 int4 stores per table
    int w1[16], w2[16];
#pragma unroll
    for (int q = 0; q < 16; q++) {
        __half2 p1 = __floats2half2_rn(a1[2*q], a1[2*q+1]);
        __half2 p2 = __floats2half2_rn(a2[2*q], a2[2*q+1]);
        w1[q] = *(int*)&p1;
        w2[q] = *(int*)&p2;
    }
    int4* rp = (int4*)(Hrh + (size_t)n * HD);
    int4* cp = (int4*)(Hch + (size_t)n * HD);
#pragma unroll
    for (int q = 0; q < 4; q++) {
        rp[q] = make_int4(w1[4*q], w1[4*q+1], w1[4*q+2], w1[4*q+3]);
        cp[q] = make_int4(w2[4*q], w2[4*q+1], w2[4*q+2], w2[4*q+3]);
    }

    cursor[n] = 0;
    float4 z4 = make_float4(0.f, 0.f, 0.f, 0.f);
    float4* za = (float4*)(aggM + (size_t)n * HD);
#pragma unroll
    for (int j = 0; j < HD/4; j++) za[j] = z4;
    ((float4*)aggX4)[n] = z4;
}

// -------- prep: pack W2 / cW1 into MFMA B-fragment order (f16), all layers --------
__global__ __launch_bounds__(128) void prep_kernel(
    const float* __restrict__ eW2, const float* __restrict__ cW1,
    __half* __restrict__ w2B, __half* __restrict__ cW1B)
{
    int l  = blockIdx.x;
    int nt = threadIdx.x >> 6;
    int wl = threadIdx.x & 63;
    int rsel = wl & 15, ksel = wl >> 4;
#pragma unroll
    for (int e = 0; e < 8; e++) {
        int k = 8 * ksel + e;
        int j = 16 * nt + rsel;
        size_t o = ((size_t)(l * 2 + nt) * 64 + wl) * 8 + e;
        w2B[o]  = __float2half(eW2[(size_t)l * HD * HD + k * HD + j]);
        cW1B[o] = __float2half(cW1[(size_t)l * HD * HD + k * HD + j]);
    }
}

// ---------------- sort prologue ----------------
__global__ __launch_bounds__(256) void hist_kernel(const int* __restrict__ row,
                                                   int* __restrict__ cnt)
{
    int e = blockIdx.x * 256 + threadIdx.x;
    if (e < NE) atomicAdd(&cnt[row[e]], 1);
}

__global__ __launch_bounds__(1024) void scanA_kernel(const int* __restrict__ cnt,
                                                     int* __restrict__ rowstart,
                                                     int* __restrict__ bsum)
{
    __shared__ int sd[1024];
    int i = blockIdx.x * 1024 + threadIdx.x;
    int v = (i < NN) ? cnt[i] : 0;
    sd[threadIdx.x] = v;
    __syncthreads();
    for (int off = 1; off < 1024; off <<= 1) {
        int t = (threadIdx.x >= (unsigned)off) ? sd[threadIdx.x - off] : 0;
        __syncthreads();
        sd[threadIdx.x] += t;
        __syncthreads();
    }
    if (i < NN) rowstart[i] = sd[threadIdx.x] - v;   // exclusive within block
    if (threadIdx.x == 1023) bsum[blockIdx.x] = sd[1023];
}

// scanC with inline block-sum scan (scanB folded in)
__global__ __launch_bounds__(1024) void scanC_kernel(int* __restrict__ rowstart,
                                                     const int* __restrict__ bsum,
                                                     int* __restrict__ cursor)
{
    __shared__ int sb[64];
    if (threadIdx.x < 64) {
        int lane = threadIdx.x;
        int v = (lane < NB_SCAN) ? bsum[lane] : 0;
        int x = v;
        for (int off = 1; off < 64; off <<= 1) {
            int y = __shfl_up(x, off);
            if (lane >= off) x += y;
        }
        sb[lane] = x - v;                            // exclusive
        if (lane == 63) rowstart[NN] = x;            // grand total (= NE), same in all blocks
    }
    __syncthreads();
    int i = blockIdx.x * 1024 + threadIdx.x;
    if (i < NN) {
        rowstart[i] += sb[blockIdx.x];
        cursor[i] = 0;                               // re-zero for scatter
    }
}

// pack {r, c, ea} into ONE scattered int4 per edge (1 dirty sector instead of 3)
__global__ __launch_bounds__(256) void scatter_kernel(
    const int* __restrict__ row, const int* __restrict__ col,
    const float* __restrict__ edge_attr,
    const int* __restrict__ rowstart, int* __restrict__ cursor,
    int4* __restrict__ sedge)
{
    int e = blockIdx.x * 256 + threadIdx.x;
    if (e >= NE) return;
    int r = row[e];
    int p = rowstart[r] + atomicAdd(&cursor[r], 1);
    sedge[p] = make_int4(r, col[e], __float_as_int(edge_attr[e]), 0);
}

// ------- fused edge kernel: epilogue(VALU) + GEMM2/coord (MFMA) + segmented agg -------
__global__ __launch_bounds__(256) void edge_fused_kernel(
    const float* __restrict__ x4,
    const int4* __restrict__ sedge,
    const __half* __restrict__ Hrh, const __half* __restrict__ Hch,
    const float* __restrict__ eW1, const float* __restrict__ eb1,
    const float* __restrict__ eb2,
    const __half* __restrict__ w2Bl, const __half* __restrict__ cW1Bl,
    const float* __restrict__ cb1, const float* __restrict__ cW2,
    const int* __restrict__ rowstart,
    float* __restrict__ aggM, float* __restrict__ aggX4)
{
    __shared__ __align__(16) __half At[256][40];   // t1 (f16), then reused for m (f16)
    __shared__ __half sx[256][4];                  // d*phi
    __shared__ float  phib[256];
    __shared__ int snf, snl;
    int tid = threadIdx.x;
    int s_base = blockIdx.x * 256;
    int s = s_base + tid;                          // NE % 256 == 0
    int4 ei = sedge[s];
    int r = ei.x, c = ei.y;
    float ea = __int_as_float(ei.z);
    if (tid == 0)   snf = r;
    if (tid == 255) snl = r;

    float4 xr = ((const float4*)x4)[r];
    float4 xc = ((const float4*)x4)[c];
    float d0 = xr.x - xc.x, d1 = xr.y - xc.y, d2 = xr.z - xc.z;
    float radial = d0*d0 + d1*d1 + d2*d2;

    // ---- P1: t1 = silu(Hr[r] + Hc[c] + radial*W1[64,:] + ea*W1[65,:] + b1) -> LDS f16
    const half8* hr8 = (const half8*)(Hrh + (size_t)r * HD);
    const half8* hc8 = (const half8*)(Hch + (size_t)c * HD);
    int wbuf[16];
#pragma unroll
    for (int i = 0; i < 4; i++) {
        half8 s8 = hr8[i] + hc8[i];          // v_pk_add_f16
#pragma unroll
        for (int k = 0; k < 8; k += 2) {
            int j = 8*i + k;
            float v0 = (float)s8[k]   + eb1[j]   + radial * eW1[64*HD+j]   + ea * eW1[65*HD+j];
            float v1 = (float)s8[k+1] + eb1[j+1] + radial * eW1[64*HD+j+1] + ea * eW1[65*HD+j+1];
            __half2 p = __floats2half2_rn(silu_f(v0), silu_f(v1));
            wbuf[(j >> 1)] = *(int*)&p;
        }
    }
    int4* arow = (int4*)&At[tid][0];
#pragma unroll
    for (int q = 0; q < 4; q++)
        arow[q] = make_int4(wbuf[4*q], wbuf[4*q+1], wbuf[4*q+2], wbuf[4*q+3]);

    int wl = tid & 63;
    int wbase = tid & 192;           // wave's private 64-row LDS window
    int rsel = wl & 15, ksel = wl >> 4;

    // ---- P2: GEMM2 via MFMA: M[64,32] = At[64,32] @ W2 + b2, silu -> m (back to LDS)
    half8 bw0 = ((const half8*)w2Bl)[wl];
    half8 bw1 = ((const half8*)w2Bl)[64 + wl];
    float bc0 = eb2[rsel], bc1 = eb2[16 + rsel];
    f32x4 acc[4][2];
#pragma unroll
    for (int mt = 0; mt < 4; mt++) {
        acc[mt][0] = (f32x4){bc0, bc0, bc0, bc0};
        acc[mt][1] = (f32x4){bc1, bc1, bc1, bc1};
    }
#pragma unroll
    for (int mt = 0; mt < 4; mt++) {
        half8 af = *(const half8*)&At[wbase + 16*mt + rsel][8*ksel];
        acc[mt][0] = __builtin_amdgcn_mfma_f32_16x16x32_f16(af, bw0, acc[mt][0], 0, 0, 0);
        acc[mt][1] = __builtin_amdgcn_mfma_f32_16x16x32_f16(af, bw1, acc[mt][1], 0, 0, 0);
    }
#pragma unroll
    for (int mt = 0; mt < 4; mt++)
#pragma unroll
        for (int nt = 0; nt < 2; nt++)
#pragma unroll
            for (int q = 0; q < 4; q++) {
                float mv = silu_f(acc[mt][nt][q]);
                At[wbase + 16*mt + 4*ksel + q][16*nt + rsel] = __float2half(mv);
            }

    // ---- P3: coord MLP via MFMA: C1[64,32] = m @ cW1 + cb1
    half8 cw0 = ((const half8*)cW1Bl)[wl];
    half8 cw1 = ((const half8*)cW1Bl)[64 + wl];
    float cc0 = cb1[rsel], cc1 = cb1[16 + rsel];
    f32x4 cacc[4][2];
#pragma unroll
    for (int mt = 0; mt < 4; mt++) {
        cacc[mt][0] = (f32x4){cc0, cc0, cc0, cc0};
        cacc[mt][1] = (f32x4){cc1, cc1, cc1, cc1};
    }
#pragma unroll
    for (int mt = 0; mt < 4; mt++) {
        half8 am = *(const half8*)&At[wbase + 16*mt + rsel][8*ksel];
        cacc[mt][0] = __builtin_amdgcn_mfma_f32_16x16x32_f16(am, cw0, cacc[mt][0], 0, 0, 0);
        cacc[mt][1] = __builtin_amdgcn_mfma_f32_16x16x32_f16(am, cw1, cacc[mt][1], 0, 0, 0);
    }

    // ---- P4: phi[row] = sum_j silu(C1[row][j]) * cW2[j]; reduce across 16-lane cols
    float cw2a = cW2[rsel], cw2b = cW2[16 + rsel];
    float p[4][4];
#pragma unroll
    for (int mt = 0; mt < 4; mt++)
#pragma unroll
        for (int q = 0; q < 4; q++)
            p[mt][q] = silu_f(cacc[mt][0][q]) * cw2a + silu_f(cacc[mt][1][q]) * cw2b;
#pragma unroll
    for (int dd = 1; dd < 16; dd <<= 1)
#pragma unroll
        for (int mt = 0; mt < 4; mt++)
#pragma unroll
            for (int q = 0; q < 4; q++)
                p[mt][q] += __shfl_xor(p[mt][q], dd);
    if (rsel == 0) {
#pragma unroll
        for (int mt = 0; mt < 4; mt++)
#pragma unroll
            for (int q = 0; q < 4; q++)
                phib[wbase + 16*mt + 4*ksel + q] = p[mt][q];
    }
    float phi = phib[tid];

    *(__half2*)&sx[tid][0] = __floats2half2_rn(d0 * phi, d1 * phi);
    sx[tid][2] = __float2half(d2 * phi);
    __syncthreads();

    // ---- P5: block-segmented reduction (m read from At as f16)
    int g = tid >> 5, ch = tid & 31;
    int nf = snf, nl = snl;
    for (int node = nf + g; node <= nl; node += 8) {
        int lo = rowstart[node], hi = rowstart[node + 1];
        int clo = lo - s_base; if (clo < 0) clo = 0;
        int chi = hi - s_base; if (chi > 256) chi = 256;
        if (chi <= clo) continue;                       // zero-degree node in range
        float am = 0.0f;
        for (int j = clo; j < chi; j++) am += __half2float(At[j][ch]);
        bool interior = (lo >= s_base) && (hi <= s_base + 256);
        if (interior) aggM[(size_t)node * HD + ch] = am;
        else          atomicAdd(&aggM[(size_t)node * HD + ch], am);
        if (ch < 3) {
            float ax = 0.0f;
            for (int j = clo; j < chi; j++) ax += __half2float(sx[j][ch]);
            if (interior) aggX4[(size_t)node * 4 + ch] = ax;
            else          atomicAdd(&aggX4[(size_t)node * 4 + ch], ax);
        }
    }
}

// ------- node update (+ f16 Hr/Hc for next layer, or fused output projection) -------
__global__ __launch_bounds__(256) void node_fused_kernel(
    float* __restrict__ h, float* __restrict__ x4,
    float* __restrict__ aggM, float* __restrict__ aggX4,
    const int* __restrict__ rowstart,
    const float* __restrict__ nW1, const float* __restrict__ nb1,
    const float* __restrict__ nW2, const float* __restrict__ nb2,
    const float* __restrict__ eW1n,   // next layer edge_w1 (null on last layer)
    __half* __restrict__ Hrh, __half* __restrict__ Hch,
    const float* __restrict__ Wout, const float* __restrict__ bout,
    float* __restrict__ out)          // non-null on last layer
{
    __shared__ float sIn[8][2*HD];
    __shared__ float sU[8][HD];
    __shared__ float sH[8][HD];
    int local = threadIdx.x >> 5;
    int ch    = threadIdx.x & 31;
    int n = blockIdx.x * 8 + local;          // NN == 6250*8, exact
    float hv = h[(size_t)n * HD + ch];
    float am = aggM[(size_t)n * HD + ch];
    aggM[(size_t)n * HD + ch] = 0.0f;        // re-zero for next layer's boundary atomics
    sIn[local][ch]      = hv;
    sIn[local][HD + ch] = am;
    if (ch < 3) {
        int cnt = rowstart[n + 1] - rowstart[n];
        float cf = (cnt < 1) ? 1.0f : (float)cnt;
        x4[(size_t)n * 4 + ch] += aggX4[(size_t)n * 4 + ch] / cf;
        aggX4[(size_t)n * 4 + ch] = 0.0f;
    }
    __syncthreads();
    float u1 = nb1[ch];
#pragma unroll 8
    for (int i = 0; i < 2*HD; i++) u1 = fmaf(sIn[local][i], nW1[i * HD + ch], u1);
    u1 = silu_f(u1);
    sU[local][ch] = u1;
    __syncthreads();
    float u2 = nb2[ch];
#pragma unroll 8
    for (int i = 0; i < HD; i++) u2 = fmaf(sU[local][i], nW2[i * HD + ch], u2);
    float hn = hv + u2;

    if (eW1n != nullptr) {
        h[(size_t)n * HD + ch] = hn;
        sH[local][ch] = hn;
        __syncthreads();
        float a = 0.0f, b = 0.0f;
#pragma unroll 8
        for (int i = 0; i < HD; i++) {
            float z = sH[local][i];
            a = fmaf(z, eW1n[i * HD + ch], a);
            b = fmaf(z, eW1n[(HD + i) * HD + ch], b);
        }
        Hrh[(size_t)n * HD + ch] = __float2half(a);
        Hch[(size_t)n * HD + ch] = __float2half(b);
    } else {
        sH[local][ch] = hn;
        __syncthreads();
        float o0 = bout[ch], o1 = bout[HD + ch];
#pragma unroll 8
        for (int i = 0; i < HD; i++) {
            float z = sH[local][i];
            o0 = fmaf(z, Wout[i * COUT + ch], o0);
            o1 = fmaf(z, Wout[i * COUT + HD + ch], o1);
        }
        out[(size_t)n * COUT + ch]      = o0;
        out[(size_t)n * COUT + HD + ch] = o1;
    }
}

extern "C" void kernel_launch(void* const* d_in, const int* in_sizes, int n_in,
                              void* d_out, int out_size, void* d_ws, size_t ws_size,
                              hipStream_t stream) {
    // setup_inputs() dict insertion order:
    //  0 data, 1 pos, 2 edge_attr, 3 t, 4 row, 5 col,
    //  6 emb_in_w, 7 emb_in_b, 8 emb_out_w, 9 emb_out_b,
    // 10 edge_w1, 11 edge_b1, 12 edge_w2, 13 edge_b2,
    // 14 node_w1, 15 node_b1, 16 node_w2, 17 node_b2,
    // 18 coord_w1, 19 coord_b1, 20 coord_w2
    const float* data      = (const float*)d_in[0];
    const float* pos       = (const float*)d_in[1];
    const float* edge_attr = (const float*)d_in[2];
    const float* tptr      = (const float*)d_in[3];
    const int*   row       = (const int*)d_in[4];
    const int*   col       = (const int*)d_in[5];
    const float* emb_in_w  = (const float*)d_in[6];
    const float* emb_in_b  = (const float*)d_in[7];
    const float* emb_out_w = (const float*)d_in[8];
    const float* emb_out_b = (const float*)d_in[9];
    const float* edge_w1   = (const float*)d_in[10];
    const float* edge_b1   = (const float*)d_in[11];
    const float* edge_w2   = (const float*)d_in[12];
    const float* edge_b2   = (const float*)d_in[13];
    const float* node_w1   = (const float*)d_in[14];
    const float* node_b1   = (const float*)d_in[15];
    const float* node_w2   = (const float*)d_in[16];
    const float* node_b2   = (const float*)d_in[17];
    const float* coord_w1  = (const float*)d_in[18];
    const float* coord_b1  = (const float*)d_in[19];
    const float* coord_w2  = (const float*)d_in[20];
    float* out = (float*)d_out;

    // workspace layout (float elements); ~8.6M floats = 34.5 MB
    float* ws = (float*)d_ws;
    float* h      = ws;                       // 1,600,000
    float* x4     = ws + 1600000;             //   200,000
    __half* Hrh   = (__half*)(ws + 1800000);  // NN*HD halfs = 800,000 floats
    __half* Hch   = (__half*)(ws + 2600000);  // 800,000
    float* aggM   = ws + 3400000;             // 1,600,000
    float* aggX4  = ws + 5000000;             //   200,000
    int* rowstart = (int*)(ws + 5200000);     // NN+1
    int* cursor   = (int*)(ws + 5250004);     // NN
    int4* sedge   = (int4*)(ws + 5400000);    // NE int4 = 3,200,000 ints
    int* bsum     = (int*)(ws + 8600000);     // 64
    __half* w2B   = (__half*)(ws + 8600100);  // NL*2*64*8 halfs
    __half* cW1B  = w2B + (size_t)NL * 1024;

    embed_kernel<<<(NN + 255) / 256, 256, 0, stream>>>(
        data, pos, tptr, emb_in_w, emb_in_b, edge_w1 /*layer 0*/,
        h, x4, Hrh, Hch, cursor, aggM, aggX4);
    prep_kernel<<<NL, 128, 0, stream>>>(edge_w2, coord_w1, w2B, cW1B);
    hist_kernel<<<NE / 256, 256, 0, stream>>>(row, cursor);
    scanA_kernel<<<NB_SCAN, 1024, 0, stream>>>(cursor, rowstart, bsum);
    scanC_kernel<<<NB_SCAN, 1024, 0, stream>>>(rowstart, bsum, cursor);
    scatter_kernel<<<NE / 256, 256, 0, stream>>>(row, col, edge_attr, rowstart, cursor, sedge);

    for (int l = 0; l < NL; l++) {
        edge_fused_kernel<<<NE / 256, 256, 0, stream>>>(
            x4, sedge, Hrh, Hch,
            edge_w1 + l * (2*HD+2) * HD, edge_b1 + l * HD,
            edge_b2 + l * HD,
            w2B + (size_t)l * 1024, cW1B + (size_t)l * 1024,
            coord_b1 + l * HD, coord_w2 + l * HD,
            rowstart, aggM, aggX4);
        bool lastl = (l + 1 == NL);
        node_fused_kernel<<<NN / 8, 256, 0, stream>>>(
            h, x4, aggM, aggX4, rowstart,
            node_w1 + l * 2 * HD * HD, node_b1 + l * HD,
            node_w2 + l * HD * HD,     node_b2 + l * HD,
            lastl ? nullptr : (edge_w1 + (l + 1) * (2*HD+2) * HD), Hrh, Hch,
            emb_out_w, emb_out_b, lastl ? out : nullptr);
    }
}

// Round 9
// 419.713 us; speedup vs baseline: 15.0645x; 1.0934x over previous
//
#include <hip/hip_runtime.h>
#include <hip/hip_fp16.h>

#define NN 50000
#define NE 800000
#define CIN 64
#define COUT 64
#define HD 32
#define NL 4
#define NBUK 196      // ceil(NN/256)
#define BUKSH 8       // bucket(r) = r >> 8
#define EPB 3125      // NE / 256 (exact)
#define MAXB 4864     // bucket capacity (mean 4096, sigma 64 -> 12 sigma headroom)

typedef float f32x4 __attribute__((ext_vector_type(4)));
typedef _Float16 half8 __attribute__((ext_vector_type(8)));

__device__ __forceinline__ float silu_f(float v) {
    return v * __builtin_amdgcn_rcpf(1.0f + __expf(-v));
}

// -------- embed: h = [t,data]@W+b ; x4=[pos,0,0]; Hr/Hc (f16) layer0; zero scratch ----
__global__ __launch_bounds__(256) void embed_kernel(
    const float* __restrict__ data, const float* __restrict__ pos,
    const float* __restrict__ tptr,
    const float* __restrict__ W, const float* __restrict__ b,
    const float* __restrict__ eW1_0,
    float* __restrict__ h, float* __restrict__ x4,
    __half* __restrict__ Hrh, __half* __restrict__ Hch,
    int* __restrict__ bcnt, float* __restrict__ aggM, float* __restrict__ aggX4)
{
    int n = blockIdx.x * 256 + threadIdx.x;
    if (n >= NN) return;
    float t = tptr[0];
    float d[CIN];
    const float4* dp = (const float4*)(data + (size_t)n * CIN);
#pragma unroll
    for (int i = 0; i < CIN / 4; i++) {
        float4 v = dp[i];
        d[4*i+0] = v.x; d[4*i+1] = v.y; d[4*i+2] = v.z; d[4*i+3] = v.w;
    }
    float acc[HD];
#pragma unroll
    for (int j = 0; j < HD; j++) acc[j] = fmaf(t, W[j], b[j]);   // row 0 = t channel
#pragma unroll
    for (int i = 0; i < CIN; i++) {
        float a = d[i];
#pragma unroll
        for (int j = 0; j < HD; j++) acc[j] = fmaf(a, W[(i + 1) * HD + j], acc[j]);
    }
    float4* hp = (float4*)(h + (size_t)n * HD);
#pragma unroll
    for (int j = 0; j < HD / 4; j++)
        hp[j] = make_float4(acc[4*j], acc[4*j+1], acc[4*j+2], acc[4*j+3]);
    ((float4*)x4)[n] = make_float4(pos[n*2+0], pos[n*2+1], 0.0f, 0.0f);

    float a1[HD], a2[HD];
#pragma unroll
    for (int j = 0; j < HD; j++) { a1[j] = 0.0f; a2[j] = 0.0f; }
#pragma unroll
    for (int i = 0; i < HD; i++) {
        float z = acc[i];
#pragma unroll
        for (int j = 0; j < HD; j++) {
            a1[j] = fmaf(z, eW1_0[i * HD + j], a1[j]);
            a2[j] = fmaf(z, eW1_0[(HD + i) * HD + j], a2[j]);
        }
    }
    // pack ALL 32 channels to f16: 16 half2 words -> 4 int4 stores per table
    int w1[16], w2[16];
#pragma unroll
    for (int q = 0; q < 16; q++) {
        __half2 p1 = __floats2half2_rn(a1[2*q], a1[2*q+1]);
        __half2 p2 = __floats2half2_rn(a2[2*q], a2[2*q+1]);
        w1[q] = *(int*)&p1;
        w2[q] = *(int*)&p2;
    }
    int4* rp = (int4*)(Hrh + (size_t)n * HD);
    int4* cp = (int4*)(Hch + (size_t)n * HD);
#pragma unroll
    for (int q = 0; q < 4; q++) {
        rp[q] = make_int4(w1[4*q], w1[4*q+1], w1[4*q+2], w1[4*q+3]);
        cp[q] = make_int4(w2[4*q], w2[4*q+1], w2[4*q+2], w2[4*q+3]);
    }

    if (n < NBUK) bcnt[n] = 0;                    // re-zero bucket counters every call
    float4 z4 = make_float4(0.f, 0.f, 0.f, 0.f);
    float4* za = (float4*)(aggM + (size_t)n * HD);
#pragma unroll
    for (int j = 0; j < HD/4; j++) za[j] = z4;
    ((float4*)aggX4)[n] = z4;
}

// -------- prep: pack W2 / cW1 into MFMA B-fragment order (f16), all layers --------
__global__ __launch_bounds__(128) void prep_kernel(
    const float* __restrict__ eW2, const float* __restrict__ cW1,
    __half* __restrict__ w2B, __half* __restrict__ cW1B)
{
    int l  = blockIdx.x;
    int nt = threadIdx.x >> 6;
    int wl = threadIdx.x & 63;
    int rsel = wl & 15, ksel = wl >> 4;
#pragma unroll
    for (int e = 0; e < 8; e++) {
        int k = 8 * ksel + e;
        int j = 16 * nt + rsel;
        size_t o = ((size_t)(l * 2 + nt) * 64 + wl) * 8 + e;
        w2B[o]  = __float2half(eW2[(size_t)l * HD * HD + k * HD + j]);
        cW1B[o] = __float2half(cW1[(size_t)l * HD * HD + k * HD + j]);
    }
}

// ================= bucket sort (no global data atomics, coalesced writes) ===========
// S1: per-block bucket histogram + reservation
__global__ __launch_bounds__(256) void sortS1_kernel(
    const int* __restrict__ row, int* __restrict__ bcnt, int* __restrict__ resv)
{
    __shared__ int lb[256];
    int tid = threadIdx.x;
    lb[tid] = 0;
    __syncthreads();
    int base = blockIdx.x * EPB;
    for (int i = tid; i < EPB; i += 256)
        atomicAdd(&lb[row[base + i] >> BUKSH], 1);
    __syncthreads();
    if (tid < NBUK)
        resv[blockIdx.x * NBUK + tid] = atomicAdd(&bcnt[tid], lb[tid]);
}

// S2: scan bucket counts -> bbase[NBUK+1]
__global__ __launch_bounds__(256) void sortS2_kernel(
    const int* __restrict__ bcnt, int* __restrict__ bbase)
{
    __shared__ int sd[256];
    int tid = threadIdx.x;
    int v = (tid < NBUK) ? bcnt[tid] : 0;
    sd[tid] = v;
    __syncthreads();
    for (int off = 1; off < 256; off <<= 1) {
        int t = (tid >= off) ? sd[tid - off] : 0;
        __syncthreads();
        sd[tid] += t;
        __syncthreads();
    }
    if (tid < NBUK) bbase[tid] = sd[tid] - v;
    if (tid == 255) bbase[NBUK] = sd[255];   // == NE
}

// S3: partition into buckets; LDS-grouped, run-coalesced global writes
__global__ __launch_bounds__(256) void sortS3_kernel(
    const int* __restrict__ row, const int* __restrict__ col,
    const float* __restrict__ eattr,
    const int* __restrict__ bbase, const int* __restrict__ resv,
    int4* __restrict__ tmp)
{
    __shared__ int4 st[EPB];           // 50 KB
    __shared__ int lb[256];
    __shared__ int lbex[NBUK];
    __shared__ int lcur[NBUK];
    __shared__ int sd[256];
    int tid = threadIdx.x;
    int base = blockIdx.x * EPB;
    lb[tid] = 0;
    if (tid < NBUK) lcur[tid] = 0;
    __syncthreads();
    for (int i = tid; i < EPB; i += 256)
        atomicAdd(&lb[row[base + i] >> BUKSH], 1);
    __syncthreads();
    int v = lb[tid];
    sd[tid] = v;
    __syncthreads();
    for (int off = 1; off < 256; off <<= 1) {
        int t = (tid >= off) ? sd[tid - off] : 0;
        __syncthreads();
        sd[tid] += t;
        __syncthreads();
    }
    if (tid < NBUK) lbex[tid] = sd[tid] - v;
    __syncthreads();
    for (int i = tid; i < EPB; i += 256) {
        int e = base + i;
        int r = row[e];
        int b = r >> BUKSH;
        int p = lbex[b] + atomicAdd(&lcur[b], 1);
        st[p] = make_int4(r, col[e], __float_as_int(eattr[e]), 0);
    }
    __syncthreads();
    int wid = tid >> 6, lane = tid & 63;
    for (int k = wid; k < NBUK; k += 4) {
        int L = lb[k];
        int g = bbase[k] + resv[blockIdx.x * NBUK + k];
        int o = lbex[k];
        for (int i = lane; i < L; i += 64)
            tmp[g + i] = st[o + i];
    }
}

// S4: within-bucket node sort; writes rowstart + sedge fully coalesced
__global__ __launch_bounds__(256) void sortS4_kernel(
    const int4* __restrict__ tmp, const int* __restrict__ bbase,
    int4* __restrict__ sedge, int* __restrict__ rowstart)
{
    __shared__ int4 st[MAXB];          // 76 KB
    __shared__ int lcnt[256], lex[256], lcur[256], sd[256];
    int tid = threadIdx.x;
    int k = blockIdx.x;
    int lo = bbase[k], hi = bbase[k + 1];
    int nE = hi - lo;
    int nodeBase = k << BUKSH;
    lcnt[tid] = 0; lcur[tid] = 0;
    __syncthreads();
    for (int i = tid; i < nE; i += 256)
        atomicAdd(&lcnt[tmp[lo + i].x - nodeBase], 1);
    __syncthreads();
    int v = lcnt[tid];
    sd[tid] = v;
    __syncthreads();
    for (int off = 1; off < 256; off <<= 1) {
        int t = (tid >= off) ? sd[tid - off] : 0;
        __syncthreads();
        sd[tid] += t;
        __syncthreads();
    }
    lex[tid] = sd[tid] - v;
    int n = nodeBase + tid;
    if (n < NN) rowstart[n] = lo + lex[tid];
    if (k == NBUK - 1 && tid == 0) rowstart[NN] = NE;
    __syncthreads();
    for (int i = tid; i < nE; i += 256) {
        int4 e = tmp[lo + i];
        int ln = e.x - nodeBase;
        int p = lex[ln] + atomicAdd(&lcur[ln], 1);
        st[p] = e;
    }
    __syncthreads();
    for (int i = tid; i < nE; i += 256)
        sedge[lo + i] = st[i];
}

// ------- fused edge kernel: epilogue(VALU) + GEMM2/coord (MFMA) + segmented agg -------
__global__ __launch_bounds__(256) void edge_fused_kernel(
    const float* __restrict__ x4,
    const int4* __restrict__ sedge,
    const __half* __restrict__ Hrh, const __half* __restrict__ Hch,
    const float* __restrict__ eW1, const float* __restrict__ eb1,
    const float* __restrict__ eb2,
    const __half* __restrict__ w2Bl, const __half* __restrict__ cW1Bl,
    const float* __restrict__ cb1, const float* __restrict__ cW2,
    const int* __restrict__ rowstart,
    float* __restrict__ aggM, float* __restrict__ aggX4)
{
    __shared__ __align__(16) __half At[256][40];   // t1 (f16), then reused for m (f16)
    __shared__ __half sx[256][4];                  // d*phi
    __shared__ float  phib[256];
    __shared__ int snf, snl;
    int tid = threadIdx.x;
    int s_base = blockIdx.x * 256;
    int s = s_base + tid;                          // NE % 256 == 0
    int4 ei = sedge[s];
    int r = ei.x, c = ei.y;
    float ea = __int_as_float(ei.z);
    if (tid == 0)   snf = r;
    if (tid == 255) snl = r;

    float4 xr = ((const float4*)x4)[r];
    float4 xc = ((const float4*)x4)[c];
    float d0 = xr.x - xc.x, d1 = xr.y - xc.y, d2 = xr.z - xc.z;
    float radial = d0*d0 + d1*d1 + d2*d2;

    // ---- P1: t1 = silu(Hr[r] + Hc[c] + radial*W1[64,:] + ea*W1[65,:] + b1) -> LDS f16
    const half8* hr8 = (const half8*)(Hrh + (size_t)r * HD);
    const half8* hc8 = (const half8*)(Hch + (size_t)c * HD);
    int wbuf[16];
#pragma unroll
    for (int i = 0; i < 4; i++) {
        half8 s8 = hr8[i] + hc8[i];          // v_pk_add_f16
#pragma unroll
        for (int kk = 0; kk < 8; kk += 2) {
            int j = 8*i + kk;
            float v0 = (float)s8[kk]   + eb1[j]   + radial * eW1[64*HD+j]   + ea * eW1[65*HD+j];
            float v1 = (float)s8[kk+1] + eb1[j+1] + radial * eW1[64*HD+j+1] + ea * eW1[65*HD+j+1];
            __half2 p = __floats2half2_rn(silu_f(v0), silu_f(v1));
            wbuf[(j >> 1)] = *(int*)&p;
        }
    }
    int4* arow = (int4*)&At[tid][0];
#pragma unroll
    for (int q = 0; q < 4; q++)
        arow[q] = make_int4(wbuf[4*q], wbuf[4*q+1], wbuf[4*q+2], wbuf[4*q+3]);

    int wl = tid & 63;
    int wbase = tid & 192;           // wave's private 64-row LDS window
    int rsel = wl & 15, ksel = wl >> 4;

    // ---- P2: GEMM2 via MFMA: M[64,32] = At[64,32] @ W2 + b2, silu -> m (back to LDS)
    half8 bw0 = ((const half8*)w2Bl)[wl];
    half8 bw1 = ((const half8*)w2Bl)[64 + wl];
    float bc0 = eb2[rsel], bc1 = eb2[16 + rsel];
    f32x4 acc[4][2];
#pragma unroll
    for (int mt = 0; mt < 4; mt++) {
        acc[mt][0] = (f32x4){bc0, bc0, bc0, bc0};
        acc[mt][1] = (f32x4){bc1, bc1, bc1, bc1};
    }
#pragma unroll
    for (int mt = 0; mt < 4; mt++) {
        half8 af = *(const half8*)&At[wbase + 16*mt + rsel][8*ksel];
        acc[mt][0] = __builtin_amdgcn_mfma_f32_16x16x32_f16(af, bw0, acc[mt][0], 0, 0, 0);
        acc[mt][1] = __builtin_amdgcn_mfma_f32_16x16x32_f16(af, bw1, acc[mt][1], 0, 0, 0);
    }
#pragma unroll
    for (int mt = 0; mt < 4; mt++)
#pragma unroll
        for (int nt = 0; nt < 2; nt++)
#pragma unroll
            for (int q = 0; q < 4; q++) {
                float mv = silu_f(acc[mt][nt][q]);
                At[wbase + 16*mt + 4*ksel + q][16*nt + rsel] = __float2half(mv);
            }

    // ---- P3: coord MLP via MFMA: C1[64,32] = m @ cW1 + cb1
    half8 cw0 = ((const half8*)cW1Bl)[wl];
    half8 cw1 = ((const half8*)cW1Bl)[64 + wl];
    float cc0 = cb1[rsel], cc1 = cb1[16 + rsel];
    f32x4 cacc[4][2];
#pragma unroll
    for (int mt = 0; mt < 4; mt++) {
        cacc[mt][0] = (f32x4){cc0, cc0, cc0, cc0};
        cacc[mt][1] = (f32x4){cc1, cc1, cc1, cc1};
    }
#pragma unroll
    for (int mt = 0; mt < 4; mt++) {
        half8 am = *(const half8*)&At[wbase + 16*mt + rsel][8*ksel];
        cacc[mt][0] = __builtin_amdgcn_mfma_f32_16x16x32_f16(am, cw0, cacc[mt][0], 0, 0, 0);
        cacc[mt][1] = __builtin_amdgcn_mfma_f32_16x16x32_f16(am, cw1, cacc[mt][1], 0, 0, 0);
    }

    // ---- P4: phi[row] = sum_j silu(C1[row][j]) * cW2[j]; reduce across 16-lane cols
    float cw2a = cW2[rsel], cw2b = cW2[16 + rsel];
    float p[4][4];
#pragma unroll
    for (int mt = 0; mt < 4; mt++)
#pragma unroll
        for (int q = 0; q < 4; q++)
            p[mt][q] = silu_f(cacc[mt][0][q]) * cw2a + silu_f(cacc[mt][1][q]) * cw2b;
#pragma unroll
    for (int dd = 1; dd < 16; dd <<= 1)
#pragma unroll
        for (int mt = 0; mt < 4; mt++)
#pragma unroll
            for (int q = 0; q < 4; q++)
                p[mt][q] += __shfl_xor(p[mt][q], dd);
    if (rsel == 0) {
#pragma unroll
        for (int mt = 0; mt < 4; mt++)
#pragma unroll
            for (int q = 0; q < 4; q++)
                phib[wbase + 16*mt + 4*ksel + q] = p[mt][q];
    }
    float phi = phib[tid];

    *(__half2*)&sx[tid][0] = __floats2half2_rn(d0 * phi, d1 * phi);
    sx[tid][2] = __float2half(d2 * phi);
    __syncthreads();

    // ---- P5: block-segmented reduction (m read from At as f16)
    int g = tid >> 5, ch = tid & 31;
    int nf = snf, nl = snl;
    for (int node = nf + g; node <= nl; node += 8) {
        int lo = rowstart[node], hi = rowstart[node + 1];
        int clo = lo - s_base; if (clo < 0) clo = 0;
        int chi = hi - s_base; if (chi > 256) chi = 256;
        if (chi <= clo) continue;                       // zero-degree node in range
        float am = 0.0f;
        for (int j = clo; j < chi; j++) am += __half2float(At[j][ch]);
        bool interior = (lo >= s_base) && (hi <= s_base + 256);
        if (interior) aggM[(size_t)node * HD + ch] = am;
        else          atomicAdd(&aggM[(size_t)node * HD + ch], am);
        if (ch < 3) {
            float ax = 0.0f;
            for (int j = clo; j < chi; j++) ax += __half2float(sx[j][ch]);
            if (interior) aggX4[(size_t)node * 4 + ch] = ax;
            else          atomicAdd(&aggX4[(size_t)node * 4 + ch], ax);
        }
    }
}

// ------- node update (+ f16 Hr/Hc for next layer, or fused output projection) -------
__global__ __launch_bounds__(256) void node_fused_kernel(
    float* __restrict__ h, float* __restrict__ x4,
    float* __restrict__ aggM, float* __restrict__ aggX4,
    const int* __restrict__ rowstart,
    const float* __restrict__ nW1, const float* __restrict__ nb1,
    const float* __restrict__ nW2, const float* __restrict__ nb2,
    const float* __restrict__ eW1n,   // next layer edge_w1 (null on last layer)
    __half* __restrict__ Hrh, __half* __restrict__ Hch,
    const float* __restrict__ Wout, const float* __restrict__ bout,
    float* __restrict__ out)          // non-null on last layer
{
    __shared__ float sIn[8][2*HD];
    __shared__ float sU[8][HD];
    __shared__ float sH[8][HD];
    int local = threadIdx.x >> 5;
    int ch    = threadIdx.x & 31;
    int n = blockIdx.x * 8 + local;          // NN == 6250*8, exact
    float hv = h[(size_t)n * HD + ch];
    float am = aggM[(size_t)n * HD + ch];
    aggM[(size_t)n * HD + ch] = 0.0f;        // re-zero for next layer's boundary atomics
    sIn[local][ch]      = hv;
    sIn[local][HD + ch] = am;
    if (ch < 3) {
        int cnt = rowstart[n + 1] - rowstart[n];
        float cf = (cnt < 1) ? 1.0f : (float)cnt;
        x4[(size_t)n * 4 + ch] += aggX4[(size_t)n * 4 + ch] / cf;
        aggX4[(size_t)n * 4 + ch] = 0.0f;
    }
    __syncthreads();
    float u1 = nb1[ch];
#pragma unroll 8
    for (int i = 0; i < 2*HD; i++) u1 = fmaf(sIn[local][i], nW1[i * HD + ch], u1);
    u1 = silu_f(u1);
    sU[local][ch] = u1;
    __syncthreads();
    float u2 = nb2[ch];
#pragma unroll 8
    for (int i = 0; i < HD; i++) u2 = fmaf(sU[local][i], nW2[i * HD + ch], u2);
    float hn = hv + u2;

    if (eW1n != nullptr) {
        h[(size_t)n * HD + ch] = hn;
        sH[local][ch] = hn;
        __syncthreads();
        float a = 0.0f, b = 0.0f;
#pragma unroll 8
        for (int i = 0; i < HD; i++) {
            float z = sH[local][i];
            a = fmaf(z, eW1n[i * HD + ch], a);
            b = fmaf(z, eW1n[(HD + i) * HD + ch], b);
        }
        Hrh[(size_t)n * HD + ch] = __float2half(a);
        Hch[(size_t)n * HD + ch] = __float2half(b);
    } else {
        sH[local][ch] = hn;
        __syncthreads();
        float o0 = bout[ch], o1 = bout[HD + ch];
#pragma unroll 8
        for (int i = 0; i < HD; i++) {
            float z = sH[local][i];
            o0 = fmaf(z, Wout[i * COUT + ch], o0);
            o1 = fmaf(z, Wout[i * COUT + HD + ch], o1);
        }
        out[(size_t)n * COUT + ch]      = o0;
        out[(size_t)n * COUT + HD + ch] = o1;
    }
}

extern "C" void kernel_launch(void* const* d_in, const int* in_sizes, int n_in,
                              void* d_out, int out_size, void* d_ws, size_t ws_size,
                              hipStream_t stream) {
    // setup_inputs() dict insertion order:
    //  0 data, 1 pos, 2 edge_attr, 3 t, 4 row, 5 col,
    //  6 emb_in_w, 7 emb_in_b, 8 emb_out_w, 9 emb_out_b,
    // 10 edge_w1, 11 edge_b1, 12 edge_w2, 13 edge_b2,
    // 14 node_w1, 15 node_b1, 16 node_w2, 17 node_b2,
    // 18 coord_w1, 19 coord_b1, 20 coord_w2
    const float* data      = (const float*)d_in[0];
    const float* pos       = (const float*)d_in[1];
    const float* edge_attr = (const float*)d_in[2];
    const float* tptr      = (const float*)d_in[3];
    const int*   row       = (const int*)d_in[4];
    const int*   col       = (const int*)d_in[5];
    const float* emb_in_w  = (const float*)d_in[6];
    const float* emb_in_b  = (const float*)d_in[7];
    const float* emb_out_w = (const float*)d_in[8];
    const float* emb_out_b = (const float*)d_in[9];
    const float* edge_w1   = (const float*)d_in[10];
    const float* edge_b1   = (const float*)d_in[11];
    const float* edge_w2   = (const float*)d_in[12];
    const float* edge_b2   = (const float*)d_in[13];
    const float* node_w1   = (const float*)d_in[14];
    const float* node_b1   = (const float*)d_in[15];
    const float* node_w2   = (const float*)d_in[16];
    const float* node_b2   = (const float*)d_in[17];
    const float* coord_w1  = (const float*)d_in[18];
    const float* coord_b1  = (const float*)d_in[19];
    const float* coord_w2  = (const float*)d_in[20];
    float* out = (float*)d_out;

    // workspace layout (float elements); ~11.9M floats = 47.6 MB (ws >= 145 MB verified R3)
    float* ws = (float*)d_ws;
    float* h      = ws;                       // 1,600,000
    float* x4     = ws + 1600000;             //   200,000
    __half* Hrh   = (__half*)(ws + 1800000);  // 800,000 floats
    __half* Hch   = (__half*)(ws + 2600000);  // 800,000
    float* aggM   = ws + 3400000;             // 1,600,000
    float* aggX4  = ws + 5000000;             //   200,000
    int* rowstart = (int*)(ws + 5200000);     // NN+1
    int* bcnt     = (int*)(ws + 5250004);     // NBUK
    int* bbase    = (int*)(ws + 5250204);     // NBUK+1
    int* resv     = (int*)(ws + 5250404);     // 256*NBUK = 50,176
    int4* sedge   = (int4*)(ws + 5400000);    // NE int4 = 3,200,000 ints (16B aligned)
    int4* tmp     = (int4*)(ws + 8600000);    // NE int4 = 3,200,000 ints (16B aligned)
    __half* w2B   = (__half*)(ws + 11800000); // NL*2*64*8 halfs
    __half* cW1B  = w2B + (size_t)NL * 1024;

    embed_kernel<<<(NN + 255) / 256, 256, 0, stream>>>(
        data, pos, tptr, emb_in_w, emb_in_b, edge_w1 /*layer 0*/,
        h, x4, Hrh, Hch, bcnt, aggM, aggX4);
    prep_kernel<<<NL, 128, 0, stream>>>(edge_w2, coord_w1, w2B, cW1B);
    sortS1_kernel<<<256, 256, 0, stream>>>(row, bcnt, resv);
    sortS2_kernel<<<1, 256, 0, stream>>>(bcnt, bbase);
    sortS3_kernel<<<256, 256, 0, stream>>>(row, col, edge_attr, bbase, resv, tmp);
    sortS4_kernel<<<NBUK, 256, 0, stream>>>(tmp, bbase, sedge, rowstart);

    for (int l = 0; l < NL; l++) {
        edge_fused_kernel<<<NE / 256, 256, 0, stream>>>(
            x4, sedge, Hrh, Hch,
            edge_w1 + l * (2*HD+2) * HD, edge_b1 + l * HD,
            edge_b2 + l * HD,
            w2B + (size_t)l * 1024, cW1B + (size_t)l * 1024,
            coord_b1 + l * HD, coord_w2 + l * HD,
            rowstart, aggM, aggX4);
        bool lastl = (l + 1 == NL);
        node_fused_kernel<<<NN / 8, 256, 0, stream>>>(
            h, x4, aggM, aggX4, rowstart,
            node_w1 + l * 2 * HD * HD, node_b1 + l * HD,
            node_w2 + l * HD * HD,     node_b2 + l * HD,
            lastl ? nullptr : (edge_w1 + (l + 1) * (2*HD+2) * HD), Hrh, Hch,
            emb_out_w, emb_out_b, lastl ? out : nullptr);
    }
}

// Round 10
// 413.293 us; speedup vs baseline: 15.2985x; 1.0155x over previous
//
#include <hip/hip_runtime.h>
#include <hip/hip_fp16.h>

#define NN 50000
#define NE 800000
#define CIN 64
#define COUT 64
#define HD 32
#define NL 4
#define NBUK 196      // ceil(NN/256)
#define BUKSH 8       // bucket(r) = r >> 8
#define EPB 3125      // NE / 256 (exact)
#define MAXB 4864     // bucket capacity (mean 4096, sigma 64 -> 12 sigma headroom)
#define BLKE 128      // edges per block in edge_fused (occupancy lever)

typedef float f32x4 __attribute__((ext_vector_type(4)));
typedef _Float16 half8 __attribute__((ext_vector_type(8)));

__device__ __forceinline__ float silu_f(float v) {
    return v * __builtin_amdgcn_rcpf(1.0f + __expf(-v));
}

// -------- embed: h = [t,data]@W+b ; x4=[pos,0,0]; Hr/Hc (f16) layer0; zero scratch ----
__global__ __launch_bounds__(256) void embed_kernel(
    const float* __restrict__ data, const float* __restrict__ pos,
    const float* __restrict__ tptr,
    const float* __restrict__ W, const float* __restrict__ b,
    const float* __restrict__ eW1_0,
    float* __restrict__ h, float* __restrict__ x4,
    __half* __restrict__ Hrh, __half* __restrict__ Hch,
    int* __restrict__ bcnt, float* __restrict__ aggM, float* __restrict__ aggX4)
{
    int n = blockIdx.x * 256 + threadIdx.x;
    if (n >= NN) return;
    float t = tptr[0];
    float d[CIN];
    const float4* dp = (const float4*)(data + (size_t)n * CIN);
#pragma unroll
    for (int i = 0; i < CIN / 4; i++) {
        float4 v = dp[i];
        d[4*i+0] = v.x; d[4*i+1] = v.y; d[4*i+2] = v.z; d[4*i+3] = v.w;
    }
    float acc[HD];
#pragma unroll
    for (int j = 0; j < HD; j++) acc[j] = fmaf(t, W[j], b[j]);   // row 0 = t channel
#pragma unroll
    for (int i = 0; i < CIN; i++) {
        float a = d[i];
#pragma unroll
        for (int j = 0; j < HD; j++) acc[j] = fmaf(a, W[(i + 1) * HD + j], acc[j]);
    }
    float4* hp = (float4*)(h + (size_t)n * HD);
#pragma unroll
    for (int j = 0; j < HD / 4; j++)
        hp[j] = make_float4(acc[4*j], acc[4*j+1], acc[4*j+2], acc[4*j+3]);
    ((float4*)x4)[n] = make_float4(pos[n*2+0], pos[n*2+1], 0.0f, 0.0f);

    float a1[HD], a2[HD];
#pragma unroll
    for (int j = 0; j < HD; j++) { a1[j] = 0.0f; a2[j] = 0.0f; }
#pragma unroll
    for (int i = 0; i < HD; i++) {
        float z = acc[i];
#pragma unroll
        for (int j = 0; j < HD; j++) {
            a1[j] = fmaf(z, eW1_0[i * HD + j], a1[j]);
            a2[j] = fmaf(z, eW1_0[(HD + i) * HD + j], a2[j]);
        }
    }
    // pack ALL 32 channels to f16: 16 half2 words -> 4 int4 stores per table
    int w1[16], w2[16];
#pragma unroll
    for (int q = 0; q < 16; q++) {
        __half2 p1 = __floats2half2_rn(a1[2*q], a1[2*q+1]);
        __half2 p2 = __floats2half2_rn(a2[2*q], a2[2*q+1]);
        w1[q] = *(int*)&p1;
        w2[q] = *(int*)&p2;
    }
    int4* rp = (int4*)(Hrh + (size_t)n * HD);
    int4* cp = (int4*)(Hch + (size_t)n * HD);
#pragma unroll
    for (int q = 0; q < 4; q++) {
        rp[q] = make_int4(w1[4*q], w1[4*q+1], w1[4*q+2], w1[4*q+3]);
        cp[q] = make_int4(w2[4*q], w2[4*q+1], w2[4*q+2], w2[4*q+3]);
    }

    if (n < NBUK) bcnt[n] = 0;                    // re-zero bucket counters every call
    float4 z4 = make_float4(0.f, 0.f, 0.f, 0.f);
    float4* za = (float4*)(aggM + (size_t)n * HD);
#pragma unroll
    for (int j = 0; j < HD/4; j++) za[j] = z4;
    ((float4*)aggX4)[n] = z4;
}

// -------- prep: pack W2 / cW1 into MFMA B-fragment order (f16), all layers --------
__global__ __launch_bounds__(128) void prep_kernel(
    const float* __restrict__ eW2, const float* __restrict__ cW1,
    __half* __restrict__ w2B, __half* __restrict__ cW1B)
{
    int l  = blockIdx.x;
    int nt = threadIdx.x >> 6;
    int wl = threadIdx.x & 63;
    int rsel = wl & 15, ksel = wl >> 4;
#pragma unroll
    for (int e = 0; e < 8; e++) {
        int k = 8 * ksel + e;
        int j = 16 * nt + rsel;
        size_t o = ((size_t)(l * 2 + nt) * 64 + wl) * 8 + e;
        w2B[o]  = __float2half(eW2[(size_t)l * HD * HD + k * HD + j]);
        cW1B[o] = __float2half(cW1[(size_t)l * HD * HD + k * HD + j]);
    }
}

// ================= bucket sort (no global data atomics, coalesced writes) ===========
// S1: per-block bucket histogram + reservation
__global__ __launch_bounds__(256) void sortS1_kernel(
    const int* __restrict__ row, int* __restrict__ bcnt, int* __restrict__ resv)
{
    __shared__ int lb[256];
    int tid = threadIdx.x;
    lb[tid] = 0;
    __syncthreads();
    int base = blockIdx.x * EPB;
    for (int i = tid; i < EPB; i += 256)
        atomicAdd(&lb[row[base + i] >> BUKSH], 1);
    __syncthreads();
    if (tid < NBUK)
        resv[blockIdx.x * NBUK + tid] = atomicAdd(&bcnt[tid], lb[tid]);
}

// S2: scan bucket counts -> bbase[NBUK+1]
__global__ __launch_bounds__(256) void sortS2_kernel(
    const int* __restrict__ bcnt, int* __restrict__ bbase)
{
    __shared__ int sd[256];
    int tid = threadIdx.x;
    int v = (tid < NBUK) ? bcnt[tid] : 0;
    sd[tid] = v;
    __syncthreads();
    for (int off = 1; off < 256; off <<= 1) {
        int t = (tid >= off) ? sd[tid - off] : 0;
        __syncthreads();
        sd[tid] += t;
        __syncthreads();
    }
    if (tid < NBUK) bbase[tid] = sd[tid] - v;
    if (tid == 255) bbase[NBUK] = sd[255];   // == NE
}

// S3: partition into buckets; LDS-grouped, run-coalesced global writes
__global__ __launch_bounds__(256) void sortS3_kernel(
    const int* __restrict__ row, const int* __restrict__ col,
    const float* __restrict__ eattr,
    const int* __restrict__ bbase, const int* __restrict__ resv,
    int4* __restrict__ tmp)
{
    __shared__ int4 st[EPB];           // 50 KB
    __shared__ int lb[256];
    __shared__ int lbex[NBUK];
    __shared__ int lcur[NBUK];
    __shared__ int sd[256];
    int tid = threadIdx.x;
    int base = blockIdx.x * EPB;
    lb[tid] = 0;
    if (tid < NBUK) lcur[tid] = 0;
    __syncthreads();
    for (int i = tid; i < EPB; i += 256)
        atomicAdd(&lb[row[base + i] >> BUKSH], 1);
    __syncthreads();
    int v = lb[tid];
    sd[tid] = v;
    __syncthreads();
    for (int off = 1; off < 256; off <<= 1) {
        int t = (tid >= off) ? sd[tid - off] : 0;
        __syncthreads();
        sd[tid] += t;
        __syncthreads();
    }
    if (tid < NBUK) lbex[tid] = sd[tid] - v;
    __syncthreads();
    for (int i = tid; i < EPB; i += 256) {
        int e = base + i;
        int r = row[e];
        int b = r >> BUKSH;
        int p = lbex[b] + atomicAdd(&lcur[b], 1);
        st[p] = make_int4(r, col[e], __float_as_int(eattr[e]), 0);
    }
    __syncthreads();
    int wid = tid >> 6, lane = tid & 63;
    for (int k = wid; k < NBUK; k += 4) {
        int L = lb[k];
        int g = bbase[k] + resv[blockIdx.x * NBUK + k];
        int o = lbex[k];
        for (int i = lane; i < L; i += 64)
            tmp[g + i] = st[o + i];
    }
}

// S4: within-bucket node sort; writes rowstart + sedge fully coalesced
__global__ __launch_bounds__(256) void sortS4_kernel(
    const int4* __restrict__ tmp, const int* __restrict__ bbase,
    int4* __restrict__ sedge, int* __restrict__ rowstart)
{
    __shared__ int4 st[MAXB];          // 76 KB
    __shared__ int lcnt[256], lex[256], lcur[256], sd[256];
    int tid = threadIdx.x;
    int k = blockIdx.x;
    int lo = bbase[k], hi = bbase[k + 1];
    int nE = hi - lo;
    int nodeBase = k << BUKSH;
    lcnt[tid] = 0; lcur[tid] = 0;
    __syncthreads();
    for (int i = tid; i < nE; i += 256)
        atomicAdd(&lcnt[tmp[lo + i].x - nodeBase], 1);
    __syncthreads();
    int v = lcnt[tid];
    sd[tid] = v;
    __syncthreads();
    for (int off = 1; off < 256; off <<= 1) {
        int t = (tid >= off) ? sd[tid - off] : 0;
        __syncthreads();
        sd[tid] += t;
        __syncthreads();
    }
    lex[tid] = sd[tid] - v;
    int n = nodeBase + tid;
    if (n < NN) rowstart[n] = lo + lex[tid];
    if (k == NBUK - 1 && tid == 0) rowstart[NN] = NE;
    __syncthreads();
    for (int i = tid; i < nE; i += 256) {
        int4 e = tmp[lo + i];
        int ln = e.x - nodeBase;
        int p = lex[ln] + atomicAdd(&lcur[ln], 1);
        st[p] = e;
    }
    __syncthreads();
    for (int i = tid; i < nE; i += 256)
        sedge[lo + i] = st[i];
}

// ------- fused edge kernel (128 edges/block): VALU epilogue + MFMA + segmented agg ----
__global__ __launch_bounds__(128, 8) void edge_fused_kernel(
    const float* __restrict__ x4,
    const int4* __restrict__ sedge,
    const __half* __restrict__ Hrh, const __half* __restrict__ Hch,
    const float* __restrict__ eW1, const float* __restrict__ eb1,
    const float* __restrict__ eb2,
    const __half* __restrict__ w2Bl, const __half* __restrict__ cW1Bl,
    const float* __restrict__ cb1, const float* __restrict__ cW2,
    const int* __restrict__ rowstart,
    float* __restrict__ aggM, float* __restrict__ aggX4)
{
    __shared__ __align__(16) __half At[BLKE][40];  // t1 (f16), then reused for m (f16)
    __shared__ __half sx[BLKE][4];                 // d*phi
    __shared__ float  phib[BLKE];
    __shared__ int snf, snl;
    int tid = threadIdx.x;
    int s_base = blockIdx.x * BLKE;
    int s = s_base + tid;                          // NE % 128 == 0
    int4 ei = sedge[s];
    int r = ei.x, c = ei.y;
    float ea = __int_as_float(ei.z);
    if (tid == 0)        snf = r;
    if (tid == BLKE - 1) snl = r;

    float4 xr = ((const float4*)x4)[r];
    float4 xc = ((const float4*)x4)[c];
    float d0 = xr.x - xc.x, d1 = xr.y - xc.y, d2 = xr.z - xc.z;
    float radial = d0*d0 + d1*d1 + d2*d2;

    // ---- P1: t1 = silu(Hr[r] + Hc[c] + radial*W1[64,:] + ea*W1[65,:] + b1) -> LDS f16
    const half8* hr8 = (const half8*)(Hrh + (size_t)r * HD);
    const half8* hc8 = (const half8*)(Hch + (size_t)c * HD);
    int wbuf[16];
#pragma unroll
    for (int i = 0; i < 4; i++) {
        half8 s8 = hr8[i] + hc8[i];          // v_pk_add_f16
#pragma unroll
        for (int kk = 0; kk < 8; kk += 2) {
            int j = 8*i + kk;
            float v0 = (float)s8[kk]   + eb1[j]   + radial * eW1[64*HD+j]   + ea * eW1[65*HD+j];
            float v1 = (float)s8[kk+1] + eb1[j+1] + radial * eW1[64*HD+j+1] + ea * eW1[65*HD+j+1];
            __half2 p = __floats2half2_rn(silu_f(v0), silu_f(v1));
            wbuf[(j >> 1)] = *(int*)&p;
        }
    }
    int4* arow = (int4*)&At[tid][0];
#pragma unroll
    for (int q = 0; q < 4; q++)
        arow[q] = make_int4(wbuf[4*q], wbuf[4*q+1], wbuf[4*q+2], wbuf[4*q+3]);

    int wl = tid & 63;
    int wbase = tid & 64;            // wave's private 64-row LDS window
    int rsel = wl & 15, ksel = wl >> 4;

    // ---- P2: GEMM2 via MFMA: M[64,32] = At[64,32] @ W2 + b2, silu -> m (back to LDS)
    half8 bw0 = ((const half8*)w2Bl)[wl];
    half8 bw1 = ((const half8*)w2Bl)[64 + wl];
    float bc0 = eb2[rsel], bc1 = eb2[16 + rsel];
    f32x4 acc[4][2];
#pragma unroll
    for (int mt = 0; mt < 4; mt++) {
        acc[mt][0] = (f32x4){bc0, bc0, bc0, bc0};
        acc[mt][1] = (f32x4){bc1, bc1, bc1, bc1};
    }
#pragma unroll
    for (int mt = 0; mt < 4; mt++) {
        half8 af = *(const half8*)&At[wbase + 16*mt + rsel][8*ksel];
        acc[mt][0] = __builtin_amdgcn_mfma_f32_16x16x32_f16(af, bw0, acc[mt][0], 0, 0, 0);
        acc[mt][1] = __builtin_amdgcn_mfma_f32_16x16x32_f16(af, bw1, acc[mt][1], 0, 0, 0);
    }
#pragma unroll
    for (int mt = 0; mt < 4; mt++)
#pragma unroll
        for (int nt = 0; nt < 2; nt++)
#pragma unroll
            for (int q = 0; q < 4; q++) {
                float mv = silu_f(acc[mt][nt][q]);
                At[wbase + 16*mt + 4*ksel + q][16*nt + rsel] = __float2half(mv);
            }

    // ---- P3: coord MLP via MFMA: C1[64,32] = m @ cW1 + cb1
    half8 cw0 = ((const half8*)cW1Bl)[wl];
    half8 cw1 = ((const half8*)cW1Bl)[64 + wl];
    float cc0 = cb1[rsel], cc1 = cb1[16 + rsel];
    f32x4 cacc[4][2];
#pragma unroll
    for (int mt = 0; mt < 4; mt++) {
        cacc[mt][0] = (f32x4){cc0, cc0, cc0, cc0};
        cacc[mt][1] = (f32x4){cc1, cc1, cc1, cc1};
    }
#pragma unroll
    for (int mt = 0; mt < 4; mt++) {
        half8 am = *(const half8*)&At[wbase + 16*mt + rsel][8*ksel];
        cacc[mt][0] = __builtin_amdgcn_mfma_f32_16x16x32_f16(am, cw0, cacc[mt][0], 0, 0, 0);
        cacc[mt][1] = __builtin_amdgcn_mfma_f32_16x16x32_f16(am, cw1, cacc[mt][1], 0, 0, 0);
    }

    // ---- P4: phi[row] = sum_j silu(C1[row][j]) * cW2[j]; reduce across 16-lane cols
    float cw2a = cW2[rsel], cw2b = cW2[16 + rsel];
    float p[4][4];
#pragma unroll
    for (int mt = 0; mt < 4; mt++)
#pragma unroll
        for (int q = 0; q < 4; q++)
            p[mt][q] = silu_f(cacc[mt][0][q]) * cw2a + silu_f(cacc[mt][1][q]) * cw2b;
#pragma unroll
    for (int dd = 1; dd < 16; dd <<= 1)
#pragma unroll
        for (int mt = 0; mt < 4; mt++)
#pragma unroll
            for (int q = 0; q < 4; q++)
                p[mt][q] += __shfl_xor(p[mt][q], dd);
    if (rsel == 0) {
#pragma unroll
        for (int mt = 0; mt < 4; mt++)
#pragma unroll
            for (int q = 0; q < 4; q++)
                phib[wbase + 16*mt + 4*ksel + q] = p[mt][q];
    }
    float phi = phib[tid];

    *(__half2*)&sx[tid][0] = __floats2half2_rn(d0 * phi, d1 * phi);
    sx[tid][2] = __float2half(d2 * phi);
    __syncthreads();

    // ---- P5: block-segmented reduction (m read from At as f16); 4 lane-groups
    int g = tid >> 5, ch = tid & 31;
    int nf = snf, nl = snl;
    for (int node = nf + g; node <= nl; node += 4) {
        int lo = rowstart[node], hi = rowstart[node + 1];
        int clo = lo - s_base; if (clo < 0) clo = 0;
        int chi = hi - s_base; if (chi > BLKE) chi = BLKE;
        if (chi <= clo) continue;                       // zero-degree node in range
        float am = 0.0f;
        for (int j = clo; j < chi; j++) am += __half2float(At[j][ch]);
        bool interior = (lo >= s_base) && (hi <= s_base + BLKE);
        if (interior) aggM[(size_t)node * HD + ch] = am;
        else          atomicAdd(&aggM[(size_t)node * HD + ch], am);
        if (ch < 3) {
            float ax = 0.0f;
            for (int j = clo; j < chi; j++) ax += __half2float(sx[j][ch]);
            if (interior) aggX4[(size_t)node * 4 + ch] = ax;
            else          atomicAdd(&aggX4[(size_t)node * 4 + ch], ax);
        }
    }
}

// ------- node update (+ f16 Hr/Hc for next layer, or fused output projection) -------
__global__ __launch_bounds__(256) void node_fused_kernel(
    float* __restrict__ h, float* __restrict__ x4,
    float* __restrict__ aggM, float* __restrict__ aggX4,
    const int* __restrict__ rowstart,
    const float* __restrict__ nW1, const float* __restrict__ nb1,
    const float* __restrict__ nW2, const float* __restrict__ nb2,
    const float* __restrict__ eW1n,   // next layer edge_w1 (null on last layer)
    __half* __restrict__ Hrh, __half* __restrict__ Hch,
    const float* __restrict__ Wout, const float* __restrict__ bout,
    float* __restrict__ out)          // non-null on last layer
{
    __shared__ float sIn[8][2*HD];
    __shared__ float sU[8][HD];
    __shared__ float sH[8][HD];
    int local = threadIdx.x >> 5;
    int ch    = threadIdx.x & 31;
    int n = blockIdx.x * 8 + local;          // NN == 6250*8, exact
    float hv = h[(size_t)n * HD + ch];
    float am = aggM[(size_t)n * HD + ch];
    aggM[(size_t)n * HD + ch] = 0.0f;        // re-zero for next layer's boundary atomics
    sIn[local][ch]      = hv;
    sIn[local][HD + ch] = am;
    if (ch < 3) {
        int cnt = rowstart[n + 1] - rowstart[n];
        float cf = (cnt < 1) ? 1.0f : (float)cnt;
        x4[(size_t)n * 4 + ch] += aggX4[(size_t)n * 4 + ch] / cf;
        aggX4[(size_t)n * 4 + ch] = 0.0f;
    }
    __syncthreads();
    float u1 = nb1[ch];
#pragma unroll 8
    for (int i = 0; i < 2*HD; i++) u1 = fmaf(sIn[local][i], nW1[i * HD + ch], u1);
    u1 = silu_f(u1);
    sU[local][ch] = u1;
    __syncthreads();
    float u2 = nb2[ch];
#pragma unroll 8
    for (int i = 0; i < HD; i++) u2 = fmaf(sU[local][i], nW2[i * HD + ch], u2);
    float hn = hv + u2;

    if (eW1n != nullptr) {
        h[(size_t)n * HD + ch] = hn;
        sH[local][ch] = hn;
        __syncthreads();
        float a = 0.0f, b = 0.0f;
#pragma unroll 8
        for (int i = 0; i < HD; i++) {
            float z = sH[local][i];
            a = fmaf(z, eW1n[i * HD + ch], a);
            b = fmaf(z, eW1n[(HD + i) * HD + ch], b);
        }
        Hrh[(size_t)n * HD + ch] = __float2half(a);
        Hch[(size_t)n * HD + ch] = __float2half(b);
    } else {
        sH[local][ch] = hn;
        __syncthreads();
        float o0 = bout[ch], o1 = bout[HD + ch];
#pragma unroll 8
        for (int i = 0; i < HD; i++) {
            float z = sH[local][i];
            o0 = fmaf(z, Wout[i * COUT + ch], o0);
            o1 = fmaf(z, Wout[i * COUT + HD + ch], o1);
        }
        out[(size_t)n * COUT + ch]      = o0;
        out[(size_t)n * COUT + HD + ch] = o1;
    }
}

extern "C" void kernel_launch(void* const* d_in, const int* in_sizes, int n_in,
                              void* d_out, int out_size, void* d_ws, size_t ws_size,
                              hipStream_t stream) {
    // setup_inputs() dict insertion order:
    //  0 data, 1 pos, 2 edge_attr, 3 t, 4 row, 5 col,
    //  6 emb_in_w, 7 emb_in_b, 8 emb_out_w, 9 emb_out_b,
    // 10 edge_w1, 11 edge_b1, 12 edge_w2, 13 edge_b2,
    // 14 node_w1, 15 node_b1, 16 node_w2, 17 node_b2,
    // 18 coord_w1, 19 coord_b1, 20 coord_w2
    const float* data      = (const float*)d_in[0];
    const float* pos       = (const float*)d_in[1];
    const float* edge_attr = (const float*)d_in[2];
    const float* tptr      = (const float*)d_in[3];
    const int*   row       = (const int*)d_in[4];
    const int*   col       = (const int*)d_in[5];
    const float* emb_in_w  = (const float*)d_in[6];
    const float* emb_in_b  = (const float*)d_in[7];
    const float* emb_out_w = (const float*)d_in[8];
    const float* emb_out_b = (const float*)d_in[9];
    const float* edge_w1   = (const float*)d_in[10];
    const float* edge_b1   = (const float*)d_in[11];
    const float* edge_w2   = (const float*)d_in[12];
    const float* edge_b2   = (const float*)d_in[13];
    const float* node_w1   = (const float*)d_in[14];
    const float* node_b1   = (const float*)d_in[15];
    const float* node_w2   = (const float*)d_in[16];
    const float* node_b2   = (const float*)d_in[17];
    const float* coord_w1  = (const float*)d_in[18];
    const float* coord_b1  = (const float*)d_in[19];
    const float* coord_w2  = (const float*)d_in[20];
    float* out = (float*)d_out;

    // workspace layout (float elements); ~11.9M floats = 47.6 MB (ws >= 145 MB verified R3)
    float* ws = (float*)d_ws;
    float* h      = ws;                       // 1,600,000
    float* x4     = ws + 1600000;             //   200,000
    __half* Hrh   = (__half*)(ws + 1800000);  // 800,000 floats
    __half* Hch   = (__half*)(ws + 2600000);  // 800,000
    float* aggM   = ws + 3400000;             // 1,600,000
    float* aggX4  = ws + 5000000;             //   200,000
    int* rowstart = (int*)(ws + 5200000);     // NN+1
    int* bcnt     = (int*)(ws + 5250004);     // NBUK
    int* bbase    = (int*)(ws + 5250204);     // NBUK+1
    int* resv     = (int*)(ws + 5250404);     // 256*NBUK = 50,176
    int4* sedge   = (int4*)(ws + 5400000);    // NE int4 = 3,200,000 ints (16B aligned)
    int4* tmp     = (int4*)(ws + 8600000);    // NE int4 = 3,200,000 ints (16B aligned)
    __half* w2B   = (__half*)(ws + 11800000); // NL*2*64*8 halfs
    __half* cW1B  = w2B + (size_t)NL * 1024;

    embed_kernel<<<(NN + 255) / 256, 256, 0, stream>>>(
        data, pos, tptr, emb_in_w, emb_in_b, edge_w1 /*layer 0*/,
        h, x4, Hrh, Hch, bcnt, aggM, aggX4);
    prep_kernel<<<NL, 128, 0, stream>>>(edge_w2, coord_w1, w2B, cW1B);
    sortS1_kernel<<<256, 256, 0, stream>>>(row, bcnt, resv);
    sortS2_kernel<<<1, 256, 0, stream>>>(bcnt, bbase);
    sortS3_kernel<<<256, 256, 0, stream>>>(row, col, edge_attr, bbase, resv, tmp);
    sortS4_kernel<<<NBUK, 256, 0, stream>>>(tmp, bbase, sedge, rowstart);

    for (int l = 0; l < NL; l++) {
        edge_fused_kernel<<<NE / BLKE, BLKE, 0, stream>>>(
            x4, sedge, Hrh, Hch,
            edge_w1 + l * (2*HD+2) * HD, edge_b1 + l * HD,
            edge_b2 + l * HD,
            w2B + (size_t)l * 1024, cW1B + (size_t)l * 1024,
            coord_b1 + l * HD, coord_w2 + l * HD,
            rowstart, aggM, aggX4);
        bool lastl = (l + 1 == NL);
        node_fused_kernel<<<NN / 8, 256, 0, stream>>>(
            h, x4, aggM, aggX4, rowstart,
            node_w1 + l * 2 * HD * HD, node_b1 + l * HD,
            node_w2 + l * HD * HD,     node_b2 + l * HD,
            lastl ? nullptr : (edge_w1 + (l + 1) * (2*HD+2) * HD), Hrh, Hch,
            emb_out_w, emb_out_b, lastl ? out : nullptr);
    }
}

// Round 11
// 411.171 us; speedup vs baseline: 15.3775x; 1.0052x over previous
//
#include <hip/hip_runtime.h>
#include <hip/hip_fp16.h>

#define NN 50000
#define NE 800000
#define CIN 64
#define COUT 64
#define HD 32
#define NL 4
#define NBUK 196      // ceil(NN/256)
#define BUKSH 8       // bucket(r) = r >> 8
#define EPB 3125      // NE / 256 (exact)
#define MAXB 4864     // bucket capacity (mean 4096, sigma 64 -> 12 sigma headroom)
#define BLKE 128      // edges per block in edge_fused
#define EMB_BLKS 196  // ceil(NN/256)

typedef float f32x4 __attribute__((ext_vector_type(4)));
typedef _Float16 half8 __attribute__((ext_vector_type(8)));

__device__ __forceinline__ float silu_f(float v) {
    return v * __builtin_amdgcn_rcpf(1.0f + __expf(-v));
}

// ========== K1: fused prologue — embed (blocks 0..195) | S1 hist (196..451) | prep (452)
__global__ __launch_bounds__(256) void prologue_kernel(
    const float* __restrict__ data, const float* __restrict__ pos,
    const float* __restrict__ tptr,
    const float* __restrict__ W, const float* __restrict__ b,
    const float* __restrict__ eW1_0,
    const int* __restrict__ row,
    const float* __restrict__ eW2, const float* __restrict__ cW1,
    float* __restrict__ h, float* __restrict__ x4,
    __half* __restrict__ Hrh, __half* __restrict__ Hch,
    float* __restrict__ aggM, float* __restrict__ aggX4,
    int* __restrict__ resv,
    __half* __restrict__ w2B, __half* __restrict__ cW1B)
{
    int blk = blockIdx.x;
    int tid = threadIdx.x;

    if (blk < EMB_BLKS) {
        // ---------------- embed role ----------------
        int n = blk * 256 + tid;
        if (n >= NN) return;
        float t = tptr[0];
        float d[CIN];
        const float4* dp = (const float4*)(data + (size_t)n * CIN);
#pragma unroll
        for (int i = 0; i < CIN / 4; i++) {
            float4 v = dp[i];
            d[4*i+0] = v.x; d[4*i+1] = v.y; d[4*i+2] = v.z; d[4*i+3] = v.w;
        }
        float acc[HD];
#pragma unroll
        for (int j = 0; j < HD; j++) acc[j] = fmaf(t, W[j], b[j]);   // row 0 = t channel
#pragma unroll
        for (int i = 0; i < CIN; i++) {
            float a = d[i];
#pragma unroll
            for (int j = 0; j < HD; j++) acc[j] = fmaf(a, W[(i + 1) * HD + j], acc[j]);
        }
        float4* hp = (float4*)(h + (size_t)n * HD);
#pragma unroll
        for (int j = 0; j < HD / 4; j++)
            hp[j] = make_float4(acc[4*j], acc[4*j+1], acc[4*j+2], acc[4*j+3]);
        ((float4*)x4)[n] = make_float4(pos[n*2+0], pos[n*2+1], 0.0f, 0.0f);

        float a1[HD], a2[HD];
#pragma unroll
        for (int j = 0; j < HD; j++) { a1[j] = 0.0f; a2[j] = 0.0f; }
#pragma unroll
        for (int i = 0; i < HD; i++) {
            float z = acc[i];
#pragma unroll
            for (int j = 0; j < HD; j++) {
                a1[j] = fmaf(z, eW1_0[i * HD + j], a1[j]);
                a2[j] = fmaf(z, eW1_0[(HD + i) * HD + j], a2[j]);
            }
        }
        int w1[16], w2[16];
#pragma unroll
        for (int q = 0; q < 16; q++) {
            __half2 p1 = __floats2half2_rn(a1[2*q], a1[2*q+1]);
            __half2 p2 = __floats2half2_rn(a2[2*q], a2[2*q+1]);
            w1[q] = *(int*)&p1;
            w2[q] = *(int*)&p2;
        }
        int4* rp = (int4*)(Hrh + (size_t)n * HD);
        int4* cp = (int4*)(Hch + (size_t)n * HD);
#pragma unroll
        for (int q = 0; q < 4; q++) {
            rp[q] = make_int4(w1[4*q], w1[4*q+1], w1[4*q+2], w1[4*q+3]);
            cp[q] = make_int4(w2[4*q], w2[4*q+1], w2[4*q+2], w2[4*q+3]);
        }
        float4 z4 = make_float4(0.f, 0.f, 0.f, 0.f);
        float4* za = (float4*)(aggM + (size_t)n * HD);
#pragma unroll
        for (int j = 0; j < HD/4; j++) za[j] = z4;
        ((float4*)aggX4)[n] = z4;
    } else if (blk < EMB_BLKS + 256) {
        // ---------------- S1 role: per-chunk bucket histogram -> resv (no atomics/global)
        __shared__ int lb[256];
        int sb = blk - EMB_BLKS;
        lb[tid] = 0;
        __syncthreads();
        int base = sb * EPB;
        for (int i = tid; i < EPB; i += 256)
            atomicAdd(&lb[row[base + i] >> BUKSH], 1);
        __syncthreads();
        if (tid < NBUK) resv[sb * NBUK + tid] = lb[tid];
    } else {
        // ---------------- prep role: pack W2 / cW1 into MFMA B-fragment order (f16)
        if (tid >= 128) return;
        int nt = tid >> 6;
        int wl = tid & 63;
        int rsel = wl & 15, ksel = wl >> 4;
        for (int l = 0; l < NL; l++) {
#pragma unroll
            for (int e = 0; e < 8; e++) {
                int k = 8 * ksel + e;
                int j = 16 * nt + rsel;
                size_t o = ((size_t)(l * 2 + nt) * 64 + wl) * 8 + e;
                w2B[o]  = __float2half(eW2[(size_t)l * HD * HD + k * HD + j]);
                cW1B[o] = __float2half(cW1[(size_t)l * HD * HD + k * HD + j]);
            }
        }
    }
}

// ========== K2: S3' — partition into buckets; inline bucket scan from resv ==========
__global__ __launch_bounds__(256) void sortS3_kernel(
    const int* __restrict__ row, const int* __restrict__ col,
    const float* __restrict__ eattr,
    const int* __restrict__ resv,
    int4* __restrict__ tmp, int* __restrict__ bbase_g)
{
    __shared__ int4 st[EPB];           // 50 KB
    __shared__ int sd[256];
    __shared__ int lcnt_s[NBUK];       // this block's per-bucket counts
    __shared__ int lbex_s[NBUK];       // exclusive scan within block
    __shared__ int g_s[NBUK];          // global write base for this block per bucket
    __shared__ int lcur[NBUK];
    int tid = threadIdx.x;
    int bb = blockIdx.x;
    int base = bb * EPB;

    int myCnt = (tid < NBUK) ? resv[bb * NBUK + tid] : 0;
    if (tid < NBUK) { lcnt_s[tid] = myCnt; lcur[tid] = 0; }
    // local exclusive scan over buckets
    sd[tid] = myCnt;
    __syncthreads();
    for (int off = 1; off < 256; off <<= 1) {
        int t = (tid >= off) ? sd[tid - off] : 0;
        __syncthreads();
        sd[tid] += t;
        __syncthreads();
    }
    if (tid < NBUK) lbex_s[tid] = sd[tid] - myCnt;
    __syncthreads();

    // bucket totals + this block's prefix within each bucket (walk resv column)
    int tot = 0, pre = 0;
    if (tid < NBUK) {
        for (int b2 = 0; b2 < 256; b2++) {
            int cv = resv[b2 * NBUK + tid];
            tot += cv;
            if (b2 < bb) pre += cv;
        }
    }
    // scan totals -> global bucket bases
    sd[tid] = (tid < NBUK) ? tot : 0;
    __syncthreads();
    for (int off = 1; off < 256; off <<= 1) {
        int t = (tid >= off) ? sd[tid - off] : 0;
        __syncthreads();
        sd[tid] += t;
        __syncthreads();
    }
    if (tid < NBUK) {
        int bbase_k = sd[tid] - tot;
        g_s[tid] = bbase_k + pre;
        if (bb == 0) bbase_g[tid] = bbase_k;
    }
    if (bb == 0 && tid == 255) bbase_g[NBUK] = sd[255];   // == NE
    __syncthreads();

    // partition this chunk's edges into LDS by bucket
    for (int i = tid; i < EPB; i += 256) {
        int e = base + i;
        int r = row[e];
        int bk = r >> BUKSH;
        int p = lbex_s[bk] + atomicAdd(&lcur[bk], 1);
        st[p] = make_int4(r, col[e], __float_as_int(eattr[e]), 0);
    }
    __syncthreads();
    // burst-write each bucket run to its reserved global slot
    int wid = tid >> 6, lane = tid & 63;
    for (int k = wid; k < NBUK; k += 4) {
        int L = lcnt_s[k];
        int g = g_s[k];
        int o = lbex_s[k];
        for (int i = lane; i < L; i += 64)
            tmp[g + i] = st[o + i];
    }
}

// ========== K3: S4 — within-bucket node sort; rowstart + sedge coalesced ==========
__global__ __launch_bounds__(256) void sortS4_kernel(
    const int4* __restrict__ tmp, const int* __restrict__ bbase,
    int4* __restrict__ sedge, int* __restrict__ rowstart)
{
    __shared__ int4 st[MAXB];          // 76 KB
    __shared__ int lcnt[256], lex[256], lcur[256], sd[256];
    int tid = threadIdx.x;
    int k = blockIdx.x;
    int lo = bbase[k], hi = bbase[k + 1];
    int nE = hi - lo;
    int nodeBase = k << BUKSH;
    lcnt[tid] = 0; lcur[tid] = 0;
    __syncthreads();
    for (int i = tid; i < nE; i += 256)
        atomicAdd(&lcnt[tmp[lo + i].x - nodeBase], 1);
    __syncthreads();
    int v = lcnt[tid];
    sd[tid] = v;
    __syncthreads();
    for (int off = 1; off < 256; off <<= 1) {
        int t = (tid >= off) ? sd[tid - off] : 0;
        __syncthreads();
        sd[tid] += t;
        __syncthreads();
    }
    lex[tid] = sd[tid] - v;
    int n = nodeBase + tid;
    if (n < NN) rowstart[n] = lo + lex[tid];
    if (k == NBUK - 1 && tid == 0) rowstart[NN] = NE;
    __syncthreads();
    for (int i = tid; i < nE; i += 256) {
        int4 e = tmp[lo + i];
        int ln = e.x - nodeBase;
        int p = lex[ln] + atomicAdd(&lcur[ln], 1);
        st[p] = e;
    }
    __syncthreads();
    for (int i = tid; i < nE; i += 256)
        sedge[lo + i] = st[i];
}

// ------- fused edge kernel (128 edges/block): VALU epilogue + MFMA + segmented agg ----
__global__ __launch_bounds__(128, 8) void edge_fused_kernel(
    const float* __restrict__ x4,
    const int4* __restrict__ sedge,
    const __half* __restrict__ Hrh, const __half* __restrict__ Hch,
    const float* __restrict__ eW1, const float* __restrict__ eb1,
    const float* __restrict__ eb2,
    const __half* __restrict__ w2Bl, const __half* __restrict__ cW1Bl,
    const float* __restrict__ cb1, const float* __restrict__ cW2,
    const int* __restrict__ rowstart,
    float* __restrict__ aggM, float* __restrict__ aggX4)
{
    __shared__ __align__(16) __half At[BLKE][40];  // t1 (f16), then reused for m (f16)
    __shared__ __half sx[BLKE][4];                 // d*phi
    __shared__ float  phib[BLKE];
    __shared__ int snf, snl;
    int tid = threadIdx.x;
    int s_base = blockIdx.x * BLKE;
    int s = s_base + tid;                          // NE % 128 == 0
    int4 ei = sedge[s];
    int r = ei.x, c = ei.y;
    float ea = __int_as_float(ei.z);
    if (tid == 0)        snf = r;
    if (tid == BLKE - 1) snl = r;

    float4 xr = ((const float4*)x4)[r];
    float4 xc = ((const float4*)x4)[c];
    float d0 = xr.x - xc.x, d1 = xr.y - xc.y, d2 = xr.z - xc.z;
    float radial = d0*d0 + d1*d1 + d2*d2;

    // ---- P1: t1 = silu(Hr[r] + Hc[c] + radial*W1[64,:] + ea*W1[65,:] + b1) -> LDS f16
    const half8* hr8 = (const half8*)(Hrh + (size_t)r * HD);
    const half8* hc8 = (const half8*)(Hch + (size_t)c * HD);
    int wbuf[16];
#pragma unroll
    for (int i = 0; i < 4; i++) {
        half8 s8 = hr8[i] + hc8[i];          // v_pk_add_f16
#pragma unroll
        for (int kk = 0; kk < 8; kk += 2) {
            int j = 8*i + kk;
            float v0 = (float)s8[kk]   + eb1[j]   + radial * eW1[64*HD+j]   + ea * eW1[65*HD+j];
            float v1 = (float)s8[kk+1] + eb1[j+1] + radial * eW1[64*HD+j+1] + ea * eW1[65*HD+j+1];
            __half2 p = __floats2half2_rn(silu_f(v0), silu_f(v1));
            wbuf[(j >> 1)] = *(int*)&p;
        }
    }
    int4* arow = (int4*)&At[tid][0];
#pragma unroll
    for (int q = 0; q < 4; q++)
        arow[q] = make_int4(wbuf[4*q], wbuf[4*q+1], wbuf[4*q+2], wbuf[4*q+3]);

    int wl = tid & 63;
    int wbase = tid & 64;            // wave's private 64-row LDS window
    int rsel = wl & 15, ksel = wl >> 4;

    // ---- P2: GEMM2 via MFMA: M[64,32] = At[64,32] @ W2 + b2, silu -> m (back to LDS)
    half8 bw0 = ((const half8*)w2Bl)[wl];
    half8 bw1 = ((const half8*)w2Bl)[64 + wl];
    float bc0 = eb2[rsel], bc1 = eb2[16 + rsel];
    f32x4 acc[4][2];
#pragma unroll
    for (int mt = 0; mt < 4; mt++) {
        acc[mt][0] = (f32x4){bc0, bc0, bc0, bc0};
        acc[mt][1] = (f32x4){bc1, bc1, bc1, bc1};
    }
    __builtin_amdgcn_s_setprio(1);
#pragma unroll
    for (int mt = 0; mt < 4; mt++) {
        half8 af = *(const half8*)&At[wbase + 16*mt + rsel][8*ksel];
        acc[mt][0] = __builtin_amdgcn_mfma_f32_16x16x32_f16(af, bw0, acc[mt][0], 0, 0, 0);
        acc[mt][1] = __builtin_amdgcn_mfma_f32_16x16x32_f16(af, bw1, acc[mt][1], 0, 0, 0);
    }
    __builtin_amdgcn_s_setprio(0);
#pragma unroll
    for (int mt = 0; mt < 4; mt++)
#pragma unroll
        for (int nt = 0; nt < 2; nt++)
#pragma unroll
            for (int q = 0; q < 4; q++) {
                float mv = silu_f(acc[mt][nt][q]);
                At[wbase + 16*mt + 4*ksel + q][16*nt + rsel] = __float2half(mv);
            }

    // ---- P3: coord MLP via MFMA: C1[64,32] = m @ cW1 + cb1
    half8 cw0 = ((const half8*)cW1Bl)[wl];
    half8 cw1 = ((const half8*)cW1Bl)[64 + wl];
    float cc0 = cb1[rsel], cc1 = cb1[16 + rsel];
    f32x4 cacc[4][2];
#pragma unroll
    for (int mt = 0; mt < 4; mt++) {
        cacc[mt][0] = (f32x4){cc0, cc0, cc0, cc0};
        cacc[mt][1] = (f32x4){cc1, cc1, cc1, cc1};
    }
    __builtin_amdgcn_s_setprio(1);
#pragma unroll
    for (int mt = 0; mt < 4; mt++) {
        half8 am = *(const half8*)&At[wbase + 16*mt + rsel][8*ksel];
        cacc[mt][0] = __builtin_amdgcn_mfma_f32_16x16x32_f16(am, cw0, cacc[mt][0], 0, 0, 0);
        cacc[mt][1] = __builtin_amdgcn_mfma_f32_16x16x32_f16(am, cw1, cacc[mt][1], 0, 0, 0);
    }
    __builtin_amdgcn_s_setprio(0);

    // ---- P4: phi[row] = sum_j silu(C1[row][j]) * cW2[j]; reduce across 16-lane cols
    float cw2a = cW2[rsel], cw2b = cW2[16 + rsel];
    float p[4][4];
#pragma unroll
    for (int mt = 0; mt < 4; mt++)
#pragma unroll
        for (int q = 0; q < 4; q++)
            p[mt][q] = silu_f(cacc[mt][0][q]) * cw2a + silu_f(cacc[mt][1][q]) * cw2b;
#pragma unroll
    for (int dd = 1; dd < 16; dd <<= 1)
#pragma unroll
        for (int mt = 0; mt < 4; mt++)
#pragma unroll
            for (int q = 0; q < 4; q++)
                p[mt][q] += __shfl_xor(p[mt][q], dd);
    if (rsel == 0) {
#pragma unroll
        for (int mt = 0; mt < 4; mt++)
#pragma unroll
            for (int q = 0; q < 4; q++)
                phib[wbase + 16*mt + 4*ksel + q] = p[mt][q];
    }
    float phi = phib[tid];

    *(__half2*)&sx[tid][0] = __floats2half2_rn(d0 * phi, d1 * phi);
    sx[tid][2] = __float2half(d2 * phi);
    __syncthreads();

    // ---- P5: block-segmented reduction (m read from At as f16); 4 lane-groups
    int g = tid >> 5, ch = tid & 31;
    int nf = snf, nl = snl;
    for (int node = nf + g; node <= nl; node += 4) {
        int lo = rowstart[node], hi = rowstart[node + 1];
        int clo = lo - s_base; if (clo < 0) clo = 0;
        int chi = hi - s_base; if (chi > BLKE) chi = BLKE;
        if (chi <= clo) continue;                       // zero-degree node in range
        float am = 0.0f;
        for (int j = clo; j < chi; j++) am += __half2float(At[j][ch]);
        bool interior = (lo >= s_base) && (hi <= s_base + BLKE);
        if (interior) aggM[(size_t)node * HD + ch] = am;
        else          atomicAdd(&aggM[(size_t)node * HD + ch], am);
        if (ch < 3) {
            float ax = 0.0f;
            for (int j = clo; j < chi; j++) ax += __half2float(sx[j][ch]);
            if (interior) aggX4[(size_t)node * 4 + ch] = ax;
            else          atomicAdd(&aggX4[(size_t)node * 4 + ch], ax);
        }
    }
}

// ------- node update (+ f16 Hr/Hc for next layer, or fused output projection) -------
__global__ __launch_bounds__(256) void node_fused_kernel(
    float* __restrict__ h, float* __restrict__ x4,
    float* __restrict__ aggM, float* __restrict__ aggX4,
    const int* __restrict__ rowstart,
    const float* __restrict__ nW1, const float* __restrict__ nb1,
    const float* __restrict__ nW2, const float* __restrict__ nb2,
    const float* __restrict__ eW1n,   // next layer edge_w1 (null on last layer)
    __half* __restrict__ Hrh, __half* __restrict__ Hch,
    const float* __restrict__ Wout, const float* __restrict__ bout,
    float* __restrict__ out)          // non-null on last layer
{
    __shared__ float sIn[8][2*HD];
    __shared__ float sU[8][HD];
    __shared__ float sH[8][HD];
    int local = threadIdx.x >> 5;
    int ch    = threadIdx.x & 31;
    int n = blockIdx.x * 8 + local;          // NN == 6250*8, exact
    float hv = h[(size_t)n * HD + ch];
    float am = aggM[(size_t)n * HD + ch];
    aggM[(size_t)n * HD + ch] = 0.0f;        // re-zero for next layer's boundary atomics
    sIn[local][ch]      = hv;
    sIn[local][HD + ch] = am;
    if (ch < 3) {
        int cnt = rowstart[n + 1] - rowstart[n];
        float cf = (cnt < 1) ? 1.0f : (float)cnt;
        x4[(size_t)n * 4 + ch] += aggX4[(size_t)n * 4 + ch] / cf;
        aggX4[(size_t)n * 4 + ch] = 0.0f;
    }
    __syncthreads();
    float u1 = nb1[ch];
#pragma unroll 8
    for (int i = 0; i < 2*HD; i++) u1 = fmaf(sIn[local][i], nW1[i * HD + ch], u1);
    u1 = silu_f(u1);
    sU[local][ch] = u1;
    __syncthreads();
    float u2 = nb2[ch];
#pragma unroll 8
    for (int i = 0; i < HD; i++) u2 = fmaf(sU[local][i], nW2[i * HD + ch], u2);
    float hn = hv + u2;

    if (eW1n != nullptr) {
        h[(size_t)n * HD + ch] = hn;
        sH[local][ch] = hn;
        __syncthreads();
        float a = 0.0f, b = 0.0f;
#pragma unroll 8
        for (int i = 0; i < HD; i++) {
            float z = sH[local][i];
            a = fmaf(z, eW1n[i * HD + ch], a);
            b = fmaf(z, eW1n[(HD + i) * HD + ch], b);
        }
        Hrh[(size_t)n * HD + ch] = __float2half(a);
        Hch[(size_t)n * HD + ch] = __float2half(b);
    } else {
        sH[local][ch] = hn;
        __syncthreads();
        float o0 = bout[ch], o1 = bout[HD + ch];
#pragma unroll 8
        for (int i = 0; i < HD; i++) {
            float z = sH[local][i];
            o0 = fmaf(z, Wout[i * COUT + ch], o0);
            o1 = fmaf(z, Wout[i * COUT + HD + ch], o1);
        }
        out[(size_t)n * COUT + ch]      = o0;
        out[(size_t)n * COUT + HD + ch] = o1;
    }
}

extern "C" void kernel_launch(void* const* d_in, const int* in_sizes, int n_in,
                              void* d_out, int out_size, void* d_ws, size_t ws_size,
                              hipStream_t stream) {
    // setup_inputs() dict insertion order:
    //  0 data, 1 pos, 2 edge_attr, 3 t, 4 row, 5 col,
    //  6 emb_in_w, 7 emb_in_b, 8 emb_out_w, 9 emb_out_b,
    // 10 edge_w1, 11 edge_b1, 12 edge_w2, 13 edge_b2,
    // 14 node_w1, 15 node_b1, 16 node_w2, 17 node_b2,
    // 18 coord_w1, 19 coord_b1, 20 coord_w2
    const float* data      = (const float*)d_in[0];
    const float* pos       = (const float*)d_in[1];
    const float* edge_attr = (const float*)d_in[2];
    const float* tptr      = (const float*)d_in[3];
    const int*   row       = (const int*)d_in[4];
    const int*   col       = (const int*)d_in[5];
    const float* emb_in_w  = (const float*)d_in[6];
    const float* emb_in_b  = (const float*)d_in[7];
    const float* emb_out_w = (const float*)d_in[8];
    const float* emb_out_b = (const float*)d_in[9];
    const float* edge_w1   = (const float*)d_in[10];
    const float* edge_b1   = (const float*)d_in[11];
    const float* edge_w2   = (const float*)d_in[12];
    const float* edge_b2   = (const float*)d_in[13];
    const float* node_w1   = (const float*)d_in[14];
    const float* node_b1   = (const float*)d_in[15];
    const float* node_w2   = (const float*)d_in[16];
    const float* node_b2   = (const float*)d_in[17];
    const float* coord_w1  = (const float*)d_in[18];
    const float* coord_b1  = (const float*)d_in[19];
    const float* coord_w2  = (const float*)d_in[20];
    float* out = (float*)d_out;

    // workspace layout (float elements); ~11.9M floats = 47.6 MB (ws >= 145 MB verified R3)
    float* ws = (float*)d_ws;
    float* h      = ws;                       // 1,600,000
    float* x4     = ws + 1600000;             //   200,000
    __half* Hrh   = (__half*)(ws + 1800000);  // 800,000 floats
    __half* Hch   = (__half*)(ws + 2600000);  // 800,000
    float* aggM   = ws + 3400000;             // 1,600,000
    float* aggX4  = ws + 5000000;             //   200,000
    int* rowstart = (int*)(ws + 5200000);     // NN+1
    int* bbase    = (int*)(ws + 5250204);     // NBUK+1
    int* resv     = (int*)(ws + 5250404);     // 256*NBUK = 50,176 (counts, written each call)
    int4* sedge   = (int4*)(ws + 5400000);    // NE int4 = 3,200,000 ints (16B aligned)
    int4* tmp     = (int4*)(ws + 8600000);    // NE int4 = 3,200,000 ints (16B aligned)
    __half* w2B   = (__half*)(ws + 11800000); // NL*2*64*8 halfs
    __half* cW1B  = w2B + (size_t)NL * 1024;

    prologue_kernel<<<EMB_BLKS + 256 + 1, 256, 0, stream>>>(
        data, pos, tptr, emb_in_w, emb_in_b, edge_w1 /*layer 0*/,
        row, edge_w2, coord_w1,
        h, x4, Hrh, Hch, aggM, aggX4, resv, w2B, cW1B);
    sortS3_kernel<<<256, 256, 0, stream>>>(row, col, edge_attr, resv, tmp, bbase);
    sortS4_kernel<<<NBUK, 256, 0, stream>>>(tmp, bbase, sedge, rowstart);

    for (int l = 0; l < NL; l++) {
        edge_fused_kernel<<<NE / BLKE, BLKE, 0, stream>>>(
            x4, sedge, Hrh, Hch,
            edge_w1 + l * (2*HD+2) * HD, edge_b1 + l * HD,
            edge_b2 + l * HD,
            w2B + (size_t)l * 1024, cW1B + (size_t)l * 1024,
            coord_b1 + l * HD, coord_w2 + l * HD,
            rowstart, aggM, aggX4);
        bool lastl = (l + 1 == NL);
        node_fused_kernel<<<NN / 8, 256, 0, stream>>>(
            h, x4, aggM, aggX4, rowstart,
            node_w1 + l * 2 * HD * HD, node_b1 + l * HD,
            node_w2 + l * HD * HD,     node_b2 + l * HD,
            lastl ? nullptr : (edge_w1 + (l + 1) * (2*HD+2) * HD), Hrh, Hch,
            emb_out_w, emb_out_b, lastl ? out : nullptr);
    }
}